// Round 14
// baseline (333.781 us; speedup 1.0000x reference)
//
#include <hip/hip_runtime.h>
#include <math.h>

#define F 64
#define VIOL_THRESH 0.2f
#define BLK_NODES 64     // 4 waves x 16 nodes
#define H_ROWB 272       // 136 bf16 per row: 68 words ≡ 4 mod 32 banks -> 2-way (free)
#define BIN_SHIFT 11
#define BIN_SIZE 2048
#define NBIN_PAD 256
#define TILE 2048

typedef float  f32x4  __attribute__((ext_vector_type(4)));
typedef short  bf16x8 __attribute__((ext_vector_type(8)));

__device__ __forceinline__ short f2bf(float f) {
    unsigned u = __builtin_bit_cast(unsigned, f);
    unsigned r = (u + 0x7fffu + ((u >> 16) & 1u)) >> 16;
    return (short)r;
}

__device__ __forceinline__ float fexp2(float x) {
#if __has_builtin(__builtin_amdgcn_exp2f)
    return __builtin_amdgcn_exp2f(x);
#else
    return exp2f(x);
#endif
}

__device__ __forceinline__ float frcp(float x) {
#if __has_builtin(__builtin_amdgcn_rcpf)
    return __builtin_amdgcn_rcpf(x);
#else
    return 1.0f / x;
#endif
}

__device__ __forceinline__ float fast_tanh(float x) {
    float xc = fminf(fmaxf(x, -9.0f), 9.0f);
    float e = fexp2(xc * 2.885390081777927f);
    return (e - 1.0f) * frcp(e + 1.0f);
}

__device__ __forceinline__ float fast_sigmoid(float z) {
    return frcp(1.0f + fexp2(-z * 1.4426950408889634f));
}

// ---------------- fused setup: zero counts/delta + weight transposes ----------------
__global__ __launch_bounds__(256)
void setup_kernel(int* __restrict__ counts, int* __restrict__ delta,
                  const float* __restrict__ w1rc, const float* __restrict__ w1cp,
                  short* __restrict__ wt1t,
                  const float* __restrict__ w2rc, const float* __restrict__ w2cp,
                  short* __restrict__ wt2t) {
    int b = blockIdx.x, tid = threadIdx.x;
    if (b == 0) { counts[tid] = 0; delta[tid] = 0; return; }
    b -= 1;
    if (b < 24) {                      // wt2t: 48*128 = 6144 elems
        int e = b * 256 + tid;
        int o = e >> 7, k = e & 127;
        float v = 0.f;
        if (o < 32)       { if (k < 64) v = w2rc[k * 32 + o]; }
        else if (o == 32) { if (k >= 64) v = w2cp[k - 64]; }
        int kp = (k & 15) * 8 + (k >> 4);
        wt2t[o * 128 + kp] = f2bf(v);
        return;
    }
    b -= 24;
    {                                  // wt1t: 128*192 = 24576 elems
        int e = b * 256 + tid;
        int o = e / 192, k = e % 192;
        const float* src = (o < 64) ? (w1rc + o) : (w1cp + (o - 64));
        wt1t[o * 192 + k] = f2bf(src[(size_t)k * 64]);
    }
}

// ---------------- count histogram (+ optional fused feature bf16 prep) ----------------
__global__ __launch_bounds__(256)
void count_prep_kernel(const int* __restrict__ e0, const int* __restrict__ e1,
                       int* __restrict__ counts, int m,
                       const float* __restrict__ feat, short* __restrict__ featbf,
                       long total, int cblocks) {
    int tid = threadIdx.x;
    if ((int)blockIdx.x < cblocks) {
        __shared__ int c[NBIN_PAD];
        c[tid] = 0;
        __syncthreads();
        for (long j = (long)blockIdx.x * 256 + tid; j < m; j += (long)cblocks * 256) {
            int u = e0[j], v = e1[j];
            if (u != v) {
                atomicAdd(&c[u >> BIN_SHIFT], 1);
                atomicAdd(&c[v >> BIN_SHIFT], 1);
            }
        }
        __syncthreads();
        if (c[tid]) atomicAdd(&counts[tid], c[tid]);
    } else {
        long t = (long)((int)blockIdx.x - cblocks) * 256 + tid;
        long base = t * 8;
        if (base >= total) return;
        float4 a = *(const float4*)(feat + base);
        float4 b = *(const float4*)(feat + base + 4);
        bf16x8 o;
        o[0] = f2bf(a.x); o[1] = f2bf(a.y); o[2] = f2bf(a.z); o[3] = f2bf(a.w);
        o[4] = f2bf(b.x); o[5] = f2bf(b.y); o[6] = f2bf(b.z); o[7] = f2bf(b.w);
        *(bf16x8*)(featbf + base) = o;
    }
}

__global__ __launch_bounds__(256)
void scatter_kernel(const int* __restrict__ e0, const int* __restrict__ e1,
                    const int* __restrict__ counts, int* __restrict__ delta,
                    unsigned* __restrict__ binned, int m) {
    __shared__ unsigned long long buf[2 * TILE];          // 32 KB
    __shared__ int goff[NBIN_PAD];
    __shared__ int tcount[NBIN_PAD], toff[NBIN_PAD], tmp[NBIN_PAD];
    __shared__ int gbase[NBIN_PAD], tcur[NBIN_PAD];
    __shared__ int totalsh;
    int tid = threadIdx.x;

    int c = counts[tid];
    tmp[tid] = c;
    __syncthreads();
    for (int off = 1; off < NBIN_PAD; off <<= 1) {
        int v = (tid >= off) ? tmp[tid - off] : 0;
        __syncthreads();
        tmp[tid] += v;
        __syncthreads();
    }
    goff[tid] = tmp[tid] - c;
    __syncthreads();

    int ntile = (m + TILE - 1) / TILE;
    for (int tile = blockIdx.x; tile < ntile; tile += gridDim.x) {
        int base = tile * TILE;
        int lim = min(TILE, m - base);
        tcount[tid] = 0;
        __syncthreads();
        for (int j = tid; j < lim; j += 256) {
            int u = e0[base + j], v = e1[base + j];
            if (u != v) {
                atomicAdd(&tcount[u >> BIN_SHIFT], 1);
                atomicAdd(&tcount[v >> BIN_SHIFT], 1);
            }
        }
        __syncthreads();
        tmp[tid] = tcount[tid];
        __syncthreads();
        for (int off = 1; off < NBIN_PAD; off <<= 1) {
            int vv = (tid >= off) ? tmp[tid - off] : 0;
            __syncthreads();
            tmp[tid] += vv;
            __syncthreads();
        }
        toff[tid] = tmp[tid] - tcount[tid];
        if (tid == NBIN_PAD - 1) totalsh = tmp[NBIN_PAD - 1];
        {
            int cct = tcount[tid];
            gbase[tid] = goff[tid] + (cct ? atomicAdd(&delta[tid], cct) : 0);
            tcur[tid] = tmp[tid] - cct;
        }
        __syncthreads();
        for (int j = tid; j < lim; j += 256) {
            int u = e0[base + j], v = e1[base + j];
            if (u != v) {
                int b1 = u >> BIN_SHIFT;
                int s1 = atomicAdd(&tcur[b1], 1);
                buf[s1] = ((unsigned long long)b1 << 32) |
                          (unsigned)(((u & (BIN_SIZE - 1)) << 19) | v);
                int b2 = v >> BIN_SHIFT;
                int s2 = atomicAdd(&tcur[b2], 1);
                buf[s2] = ((unsigned long long)b2 << 32) |
                          (unsigned)(((v & (BIN_SIZE - 1)) << 19) | u);
            }
        }
        __syncthreads();
        int total = totalsh;
        for (int t = tid; t < total; t += 256) {
            unsigned long long e = buf[t];
            int b = (int)(e >> 32);
            binned[gbase[b] + (t - toff[b])] = (unsigned)e;
        }
        __syncthreads();
    }
}

__global__ __launch_bounds__(256)
void process_kernel(const unsigned* __restrict__ binned, const int* __restrict__ counts,
                    int* __restrict__ min1, int* __restrict__ min2, int n) {
    __shared__ int m1s[BIN_SIZE], m2s[BIN_SIZE];   // 16 KB
    __shared__ int tmp[NBIN_PAD];
    __shared__ int s_sh, e_sh;
    int tid = threadIdx.x, b = blockIdx.x;
    int c = counts[tid];
    tmp[tid] = c;
    __syncthreads();
    for (int off = 1; off < NBIN_PAD; off <<= 1) {
        int v = (tid >= off) ? tmp[tid - off] : 0;
        __syncthreads();
        tmp[tid] += v;
        __syncthreads();
    }
    if (tid == b) { e_sh = tmp[tid]; s_sh = tmp[tid] - c; }
    for (int i = tid; i < BIN_SIZE; i += 256) { m1s[i] = n; m2s[i] = n; }
    __syncthreads();
    int s = s_sh, e = e_sh;
    for (int j = s + tid; j < e; j += 256) {
        unsigned p = binned[j];
        atomicMin(&m1s[p >> 19], (int)(p & 0x7FFFFu));
    }
    __syncthreads();
    for (int j = s + tid; j < e; j += 256) {
        unsigned p = binned[j];
        int lu = p >> 19, v = (int)(p & 0x7FFFFu);
        if (v != m1s[lu]) atomicMin(&m2s[lu], v);
    }
    __syncthreads();
    int gb = b << BIN_SHIFT;
    for (int i = tid; i < BIN_SIZE; i += 256) {
        int g = gb + i;
        if (g < n) { min1[g] = m1s[i]; min2[g] = m2s[i]; }
    }
}

// ---------------- device-scope fallback ----------------
__global__ void init_min12(int* __restrict__ min1, int* __restrict__ min2, int n) {
    int i = blockIdx.x * blockDim.x + threadIdx.x;
    if (i < n) { min1[i] = n; min2[i] = n; }
}

__device__ __forceinline__ void upd_min1(int u, int v, int* __restrict__ min1) {
    if (u != v) {
        if (v < min1[u]) atomicMin(&min1[u], v);
        if (u < min1[v]) atomicMin(&min1[v], u);
    }
}

__global__ void edge_min1_kernel(const int* __restrict__ e0, const int* __restrict__ e1,
                                 int* __restrict__ min1, int m) {
    int t = blockIdx.x * blockDim.x + threadIdx.x;
    int base = t * 4;
    if (base >= m) return;
    if (base + 4 <= m) {
        int4 u4 = *(const int4*)(e0 + base);
        int4 v4 = *(const int4*)(e1 + base);
        upd_min1(u4.x, v4.x, min1);
        upd_min1(u4.y, v4.y, min1);
        upd_min1(u4.z, v4.z, min1);
        upd_min1(u4.w, v4.w, min1);
    } else {
        for (int j = base; j < m; j++) upd_min1(e0[j], e1[j], min1);
    }
}

__device__ __forceinline__ void upd_min2(int u, int v, const int* __restrict__ min1,
                                         int* __restrict__ min2) {
    if (u != v) {
        if (v != min1[u] && v < min2[u]) atomicMin(&min2[u], v);
        if (u != min1[v] && u < min2[v]) atomicMin(&min2[v], u);
    }
}

__global__ void edge_min2_kernel(const int* __restrict__ e0, const int* __restrict__ e1,
                                 const int* __restrict__ min1, int* __restrict__ min2, int m) {
    int t = blockIdx.x * blockDim.x + threadIdx.x;
    int base = t * 4;
    if (base >= m) return;
    if (base + 4 <= m) {
        int4 u4 = *(const int4*)(e0 + base);
        int4 v4 = *(const int4*)(e1 + base);
        upd_min2(u4.x, v4.x, min1, min2);
        upd_min2(u4.y, v4.y, min1, min2);
        upd_min2(u4.z, v4.z, min1, min2);
        upd_min2(u4.w, v4.w, min1, min2);
    } else {
        for (int j = base; j < m; j++) upd_min2(e0[j], e1[j], min1, min2);
    }
}

// ---------------- standalone feature bf16 prep ----------------
__global__ void prep_feat(const float* __restrict__ f, short* __restrict__ fb, long total) {
    long t = (long)blockIdx.x * blockDim.x + threadIdx.x;
    long base = t * 8;
    if (base >= total) return;
    float4 a = *(const float4*)(f + base);
    float4 b = *(const float4*)(f + base + 4);
    bf16x8 o;
    o[0] = f2bf(a.x); o[1] = f2bf(a.y); o[2] = f2bf(a.z); o[3] = f2bf(a.w);
    o[4] = f2bf(b.x); o[5] = f2bf(b.y); o[6] = f2bf(b.z); o[7] = f2bf(b.w);
    *(bf16x8*)(fb + base) = o;
}

// ---------------- fused node + feature-update kernel: 1 m-tile (16 nodes) per wave ----------------
template<bool BF>
__global__ __launch_bounds__(256)
void node_kernel(const float* __restrict__ feat, const short* __restrict__ featbf,
                 const float* __restrict__ radii,
                 const float* __restrict__ b1rc, const float* __restrict__ b2rc,
                 const float* __restrict__ w3rc, const float* __restrict__ b3rc,
                 const float* __restrict__ b1cp, const float* __restrict__ b2cp,
                 const short* __restrict__ wt1t, const short* __restrict__ wt2t,
                 const int* __restrict__ types,
                 const int* __restrict__ min1, const int* __restrict__ min2,
                 float* __restrict__ out, float4* __restrict__ partials,
                 int n) {
    // No __syncthreads: each wave touches ONLY its own 16-node slice of LDS.
    __shared__ __align__(16) char Hbuf[BLK_NODES * H_ROWB];   // 17408 B
    __shared__ float corrArr[BLK_NODES];
    __shared__ float zArr[BLK_NODES];
    __shared__ float gateArr[BLK_NODES];

    int tid = threadIdx.x;
    int blk = blockIdx.x;
    int lane = tid & 63;
    int w = tid >> 6;
    int lm = lane & 15;
    int lg = lane >> 4;
    int wnb = w * 16;           // wave's 16-node slice

    // node ids for this wave's m-tile
    int nid[3];
    {
        int g = blk * BLK_NODES + wnb + lm;
        int ii = (g < n) ? g : (n - 1);
        int m1 = min1[ii];
        int m2 = min2[ii];
        nid[0] = ii;
        nid[1] = (m1 < n) ? m1 : (n - 1);
        nid[2] = (m2 < n) ? m2 : (n - 1);
    }

    // ---- early epilogue prefetch (lanes 16-63 mirror 0-15) ----
    int el = lane & 15;
    int eg = blk * BLK_NODES + wnb + el;
    bool elive = eg < n;
    int eii = elive ? eg : (n - 1);
    int em2 = min2[eii];
    float er0 = radii[eii];
    int ety = types[eii];
    int em1 = min1[eii];
    int ec1 = (em1 < n) ? em1 : (n - 1);
    int ec2 = (em2 < n) ? em2 : (n - 1);
    float er1 = radii[ec1];
    float er2 = radii[ec2];

    // ---- prefetch all 6 layer-1 A-fragments ----
    bf16x8 af[3][2];
    if constexpr (BF) {
#pragma unroll
        for (int part = 0; part < 3; part++)
#pragma unroll
            for (int h = 0; h < 2; h++)
                af[part][h] = *(const bf16x8*)(featbf + (size_t)nid[part] * F + h * 32 + lg * 8);
    }

    // ---------- layer 1: H[16 nodes][128 outs] ----------
    f32x4 zero4 = {0.f, 0.f, 0.f, 0.f};
    f32x4 acc[8];
#pragma unroll
    for (int nt = 0; nt < 8; nt++) acc[nt] = zero4;

#pragma unroll
    for (int s = 0; s < 6; s++) {
        int part = s >> 1;
        int h = s & 1;
        bf16x8 a0;
        if constexpr (BF) {
            a0 = af[part][h];
        } else {
            const float* rp = feat + (size_t)nid[part] * F + h * 32 + lg * 8;
            float4 f0 = *(const float4*)rp;
            float4 f1 = *(const float4*)(rp + 4);
            bf16x8 a;
            a[0] = f2bf(f0.x); a[1] = f2bf(f0.y); a[2] = f2bf(f0.z); a[3] = f2bf(f0.w);
            a[4] = f2bf(f1.x); a[5] = f2bf(f1.y); a[6] = f2bf(f1.z); a[7] = f2bf(f1.w);
            a0 = a;
        }
#pragma unroll
        for (int nt = 0; nt < 8; nt++) {
            bf16x8 b = *(const bf16x8*)(wt1t + (lm + 16 * nt) * 192 + s * 32 + lg * 8);
            acc[nt] = __builtin_amdgcn_mfma_f32_16x16x32_bf16(a0, b, acc[nt], 0, 0, 0);
        }
    }

    float b1v[8];
#pragma unroll
    for (int nt = 0; nt < 8; nt++)
        b1v[nt] = (nt < 4) ? b1rc[lm + 16 * nt] : b1cp[lm + 16 * nt - 64];

    // packed H store: row layout o_perm = lm*8 + nt -> one ds_write_b128 per r
#pragma unroll
    for (int r = 0; r < 4; r++) {
        int node = wnb + lg * 4 + r;
        bf16x8 hv;
#pragma unroll
        for (int nt = 0; nt < 8; nt++)
            hv[nt] = f2bf(fmaxf(acc[nt][r] + b1v[nt], 0.f));
        *(bf16x8*)(Hbuf + node * H_ROWB + lm * 16) = hv;
    }

    // ---------- layer 2: [16 nodes][33 of 48] ----------
    f32x4 acc2[3];
#pragma unroll
    for (int nt = 0; nt < 3; nt++) acc2[nt] = zero4;

#pragma unroll
    for (int s = 0; s < 4; s++) {
        bf16x8 af2 = *(const bf16x8*)(Hbuf + (wnb + lm) * H_ROWB + s * 64 + lg * 16);
#pragma unroll
        for (int nt = 0; nt < 3; nt++) {
            bf16x8 b = *(const bf16x8*)(wt2t + (lm + 16 * nt) * 128 + s * 32 + lg * 8);
            acc2[nt] = __builtin_amdgcn_mfma_f32_16x16x32_bf16(af2, b, acc2[nt], 0, 0, 0);
        }
    }

    // corr / z per node
#pragma unroll
    for (int r = 0; r < 4; r++) {
        float t = 0.f;
#pragma unroll
        for (int nt = 0; nt < 2; nt++) {
            int o = lm + 16 * nt;
            float s2v = fmaxf(acc2[nt][r] + b2rc[o], 0.f);
            t = fmaf(s2v, w3rc[o], t);
        }
        float zz = acc2[2][r];
#pragma unroll
        for (int msk = 1; msk < 16; msk <<= 1) {
            t  += __shfl_xor(t, msk);
            zz += __shfl_xor(zz, msk);
        }
        if (lm == 0) {
            int node = wnb + lg * 4 + r;
            corrArr[node] = t + b3rc[0];
            zArr[node]    = zz + b2cp[0];
        }
    }

    // ---------- per-wave epilogue (lanes 0-15; prefetched values) ----------
    float sv = 0.f, sc = 0.f, ct = 0.f;
    if (lane < 16) {
        bool valid = em2 < n;
        float pr3 = er0 * er0 * er0;
        float viol = fabsf(er1 * er1 * er1 + er2 * er2 * er2 - pr3) / pr3;
        bool active = elive && valid && (ety == 1);
        bool upd = active && (viol > VIOL_THRESH);
        float gate = upd ? corrArr[wnb + el] : 0.f;
        gateArr[wnb + el] = 0.1f * gate;
        if (active) {
            sv = viol;
            sc = fast_sigmoid(zArr[wnb + el]);
            ct = 1.f;
        }
    }
#pragma unroll
    for (int off = 32; off > 0; off >>= 1) {
        sv += __shfl_down(sv, off);
        sc += __shfl_down(sc, off);
        ct += __shfl_down(ct, off);
    }
    if (lane == 0) {
        float4 p; p.x = sv; p.y = sc; p.z = ct; p.w = 0.f;
        partials[blk * 4 + w] = p;
    }

    // ---------- fused feature update: wave streams its own contiguous 4 KB ----------
    {
        size_t wbase = (size_t)(blk * BLK_NODES + wnb) * F;
        const float* fsrc = feat + wbase;
        float* fdst = out + wbase;
#pragma unroll
        for (int q = 0; q < 4; q++) {
            int elem = q * 256 + lane * 4;
            int nloc = wnb + (elem >> 6);
            int g = blk * BLK_NODES + nloc;
            if (g < n) {
                float gate01 = gateArr[nloc];
                float4 v = *(const float4*)(fsrc + elem);
                float4 r;
                r.x = v.x + gate01 * fast_tanh(v.x);
                r.y = v.y + gate01 * fast_tanh(v.y);
                r.z = v.z + gate01 * fast_tanh(v.z);
                r.w = v.w + gate01 * fast_tanh(v.w);
                *(float4*)(fdst + elem) = r;
            }
        }
    }
}

__global__ __launch_bounds__(256)
void finalize_kernel(const float4* __restrict__ partials, int np,
                     float* __restrict__ out_scalars) {
    __shared__ float red[3][4];
    int tid = threadIdx.x;
    float sv = 0.f, sc = 0.f, ct = 0.f;
    for (int i = tid; i < np; i += 256) {
        float4 p = partials[i];
        sv += p.x; sc += p.y; ct += p.z;
    }
#pragma unroll
    for (int off = 32; off > 0; off >>= 1) {
        sv += __shfl_down(sv, off);
        sc += __shfl_down(sc, off);
        ct += __shfl_down(ct, off);
    }
    int lane = tid & 63, w = tid >> 6;
    if (lane == 0) { red[0][w] = sv; red[1][w] = sc; red[2][w] = ct; }
    __syncthreads();
    if (tid == 0) {
        float tv = red[0][0] + red[0][1] + red[0][2] + red[0][3];
        float tc = red[1][0] + red[1][1] + red[1][2] + red[1][3];
        float tn = red[2][0] + red[2][1] + red[2][2] + red[2][3];
        float d = tn > 1.f ? tn : 1.f;
        out_scalars[0] = tv / d;
        out_scalars[1] = tc / d;
    }
}

extern "C" void kernel_launch(void* const* d_in, const int* in_sizes, int n_in,
                              void* d_out, int out_size, void* d_ws, size_t ws_size,
                              hipStream_t stream) {
    const float* feat  = (const float*)d_in[0];
    const float* radii = (const float*)d_in[1];
    const float* w1rc  = (const float*)d_in[2];
    const float* b1rc  = (const float*)d_in[3];
    const float* w2rc  = (const float*)d_in[4];
    const float* b2rc  = (const float*)d_in[5];
    const float* w3rc  = (const float*)d_in[6];
    const float* b3rc  = (const float*)d_in[7];
    const float* w1cp  = (const float*)d_in[8];
    const float* b1cp  = (const float*)d_in[9];
    const float* w2cp  = (const float*)d_in[10];
    const float* b2cp  = (const float*)d_in[11];
    const int*   eidx  = (const int*)d_in[12];
    const int*   types = (const int*)d_in[13];

    int n = in_sizes[0] / F;          // 300000
    int m = in_sizes[12] / 2;         // 3000000

    int nblocks = (n + BLK_NODES - 1) / BLK_NODES;
    int np = nblocks * 4;
    int nbins = (n + BIN_SIZE - 1) >> BIN_SHIFT;

    // ws layout: wt1t | wt2t | min1 | min2 | partials | counts | delta | [binned][featbf]
    char* ws = (char*)d_ws;
    short* wt1t = (short*)ws;                            ws += 128 * 192 * 2;
    short* wt2t = (short*)ws;                            ws += 48 * 128 * 2;
    int* min1 = (int*)ws;                                ws += (size_t)n * 4;
    int* min2 = (int*)ws;                                ws += (size_t)n * 4;
    float4* partials = (float4*)ws;                      ws += (size_t)np * 16;
    int* counts = (int*)ws;                              ws += NBIN_PAD * 4;
    int* delta  = (int*)ws;                              ws += NBIN_PAD * 4;

    size_t used = (size_t)(ws - (char*)d_ws);
    size_t binned_bytes = (size_t)2 * m * 4;
    size_t featbf_bytes = (size_t)n * F * 2;

    bool useBinned = (n < (1 << 19)) && (nbins <= NBIN_PAD) && (used + binned_bytes <= ws_size);
    bool sepBuf    = useBinned && (used + binned_bytes + featbf_bytes <= ws_size);
    unsigned* binned = (unsigned*)ws;
    short* featbf;
    bool useBF;
    if (sepBuf) {
        featbf = (short*)(ws + binned_bytes);
        useBF = true;
    } else {
        featbf = (short*)ws;   // overlays binned (sequential use)
        useBF = (used + featbf_bytes) <= ws_size;
    }

    float* out         = (float*)d_out;
    float* out_scalars = out + (size_t)n * F;

    int bs = 256;
    const int* e0 = eidx;
    const int* e1 = eidx + m;
    long total = (long)n * F;
    long prepthr = total / 8;
    int prepblocks = (int)((prepthr + bs - 1) / bs);

    // -------- setup (zero counts/delta + weight transposes) --------
    setup_kernel<<<121, bs, 0, stream>>>(counts, delta, w1rc, w1cp, wt1t, w2rc, w2cp, wt2t);

    // -------- edge phase --------
    if (useBinned) {
        if (sepBuf && useBF) {
            count_prep_kernel<<<1024 + prepblocks, bs, 0, stream>>>(
                e0, e1, counts, m, feat, featbf, total, 1024);
        } else {
            count_prep_kernel<<<1024, bs, 0, stream>>>(
                e0, e1, counts, m, feat, featbf, 0, 1024);
        }
        scatter_kernel<<<768, bs, 0, stream>>>(e0, e1, counts, delta, binned, m);
        process_kernel<<<nbins, bs, 0, stream>>>(binned, counts, min1, min2, n);
        if (!sepBuf && useBF)
            prep_feat<<<prepblocks, bs, 0, stream>>>(feat, featbf, total);
    } else {
        int mt4 = (m + 3) / 4;
        init_min12<<<(n + bs - 1) / bs, bs, 0, stream>>>(min1, min2, n);
        edge_min1_kernel<<<(mt4 + bs - 1) / bs, bs, 0, stream>>>(e0, e1, min1, m);
        edge_min2_kernel<<<(mt4 + bs - 1) / bs, bs, 0, stream>>>(e0, e1, min1, min2, m);
        if (useBF)
            prep_feat<<<prepblocks, bs, 0, stream>>>(feat, featbf, total);
    }

    // -------- fused node + update --------
    if (useBF) {
        node_kernel<true><<<nblocks, bs, 0, stream>>>(
            feat, featbf, radii, b1rc, b2rc, w3rc, b3rc, b1cp, b2cp,
            wt1t, wt2t, types, min1, min2, out, partials, n);
    } else {
        node_kernel<false><<<nblocks, bs, 0, stream>>>(
            feat, featbf, radii, b1rc, b2rc, w3rc, b3rc, b1cp, b2cp,
            wt1t, wt2t, types, min1, min2, out, partials, n);
    }
    finalize_kernel<<<1, 256, 0, stream>>>(partials, np, out_scalars);
}

// Round 15
// 283.346 us; speedup vs baseline: 1.1780x; 1.1780x over previous
//
#include <hip/hip_runtime.h>
#include <math.h>

#define F 64
#define VIOL_THRESH 0.2f
#define BLK_NODES 128
#define H_ROWB 272   // 136 bf16 per row: 68 words ≡ 4 mod 32 banks -> 2-way (free)
#define BIN_SHIFT 11
#define BIN_SIZE 2048
#define NBIN_PAD 256
#define TILE 2048

typedef float  f32x4  __attribute__((ext_vector_type(4)));
typedef short  bf16x8 __attribute__((ext_vector_type(8)));

__device__ __forceinline__ short f2bf(float f) {
    unsigned u = __builtin_bit_cast(unsigned, f);
    unsigned r = (u + 0x7fffu + ((u >> 16) & 1u)) >> 16;
    return (short)r;
}

__device__ __forceinline__ float fexp2(float x) {
#if __has_builtin(__builtin_amdgcn_exp2f)
    return __builtin_amdgcn_exp2f(x);
#else
    return exp2f(x);
#endif
}

__device__ __forceinline__ float frcp(float x) {
#if __has_builtin(__builtin_amdgcn_rcpf)
    return __builtin_amdgcn_rcpf(x);
#else
    return 1.0f / x;
#endif
}

__device__ __forceinline__ float fast_tanh(float x) {
    float xc = fminf(fmaxf(x, -9.0f), 9.0f);
    float e = fexp2(xc * 2.885390081777927f);
    return (e - 1.0f) * frcp(e + 1.0f);
}

__device__ __forceinline__ float fast_sigmoid(float z) {
    return frcp(1.0f + fexp2(-z * 1.4426950408889634f));
}

// ---------------- fused setup: zero counts/delta + weight transposes ----------------
__global__ __launch_bounds__(256)
void setup_kernel(int* __restrict__ counts, int* __restrict__ delta,
                  const float* __restrict__ w1rc, const float* __restrict__ w1cp,
                  short* __restrict__ wt1t,
                  const float* __restrict__ w2rc, const float* __restrict__ w2cp,
                  short* __restrict__ wt2t) {
    int b = blockIdx.x, tid = threadIdx.x;
    if (b == 0) { counts[tid] = 0; delta[tid] = 0; return; }
    b -= 1;
    if (b < 24) {                      // wt2t: 48*128 = 6144 elems
        int e = b * 256 + tid;
        int o = e >> 7, k = e & 127;
        float v = 0.f;
        if (o < 32)       { if (k < 64) v = w2rc[k * 32 + o]; }
        else if (o == 32) { if (k >= 64) v = w2cp[k - 64]; }
        int kp = (k & 15) * 8 + (k >> 4);
        wt2t[o * 128 + kp] = f2bf(v);
        return;
    }
    b -= 24;
    {                                  // wt1t: 128*192 = 24576 elems
        int e = b * 256 + tid;
        int o = e / 192, k = e % 192;
        const float* src = (o < 64) ? (w1rc + o) : (w1cp + (o - 64));
        wt1t[o * 192 + k] = f2bf(src[(size_t)k * 64]);
    }
}

// ---------------- count histogram (+ optional fused feature bf16 prep) ----------------
__global__ __launch_bounds__(256)
void count_prep_kernel(const int* __restrict__ e0, const int* __restrict__ e1,
                       int* __restrict__ counts, int m,
                       const float* __restrict__ feat, short* __restrict__ featbf,
                       long total, int cblocks) {
    int tid = threadIdx.x;
    if ((int)blockIdx.x < cblocks) {
        __shared__ int c[NBIN_PAD];
        c[tid] = 0;
        __syncthreads();
        for (long j = (long)blockIdx.x * 256 + tid; j < m; j += (long)cblocks * 256) {
            int u = e0[j], v = e1[j];
            if (u != v) {
                atomicAdd(&c[u >> BIN_SHIFT], 1);
                atomicAdd(&c[v >> BIN_SHIFT], 1);
            }
        }
        __syncthreads();
        if (c[tid]) atomicAdd(&counts[tid], c[tid]);
    } else {
        long t = (long)((int)blockIdx.x - cblocks) * 256 + tid;
        long base = t * 8;
        if (base >= total) return;
        float4 a = *(const float4*)(feat + base);
        float4 b = *(const float4*)(feat + base + 4);
        bf16x8 o;
        o[0] = f2bf(a.x); o[1] = f2bf(a.y); o[2] = f2bf(a.z); o[3] = f2bf(a.w);
        o[4] = f2bf(b.x); o[5] = f2bf(b.y); o[6] = f2bf(b.z); o[7] = f2bf(b.w);
        *(bf16x8*)(featbf + base) = o;
    }
}

__global__ __launch_bounds__(256)
void scatter_kernel(const int* __restrict__ e0, const int* __restrict__ e1,
                    const int* __restrict__ counts, int* __restrict__ delta,
                    unsigned* __restrict__ binned, int m) {
    __shared__ unsigned long long buf[2 * TILE];          // 32 KB
    __shared__ int goff[NBIN_PAD];
    __shared__ int tcount[NBIN_PAD], toff[NBIN_PAD], tmp[NBIN_PAD];
    __shared__ int gbase[NBIN_PAD], tcur[NBIN_PAD];
    __shared__ int totalsh;
    int tid = threadIdx.x;

    int c = counts[tid];
    tmp[tid] = c;
    __syncthreads();
    for (int off = 1; off < NBIN_PAD; off <<= 1) {
        int v = (tid >= off) ? tmp[tid - off] : 0;
        __syncthreads();
        tmp[tid] += v;
        __syncthreads();
    }
    goff[tid] = tmp[tid] - c;
    __syncthreads();

    int ntile = (m + TILE - 1) / TILE;
    for (int tile = blockIdx.x; tile < ntile; tile += gridDim.x) {
        int base = tile * TILE;
        int lim = min(TILE, m - base);
        tcount[tid] = 0;
        __syncthreads();
        for (int j = tid; j < lim; j += 256) {
            int u = e0[base + j], v = e1[base + j];
            if (u != v) {
                atomicAdd(&tcount[u >> BIN_SHIFT], 1);
                atomicAdd(&tcount[v >> BIN_SHIFT], 1);
            }
        }
        __syncthreads();
        tmp[tid] = tcount[tid];
        __syncthreads();
        for (int off = 1; off < NBIN_PAD; off <<= 1) {
            int vv = (tid >= off) ? tmp[tid - off] : 0;
            __syncthreads();
            tmp[tid] += vv;
            __syncthreads();
        }
        toff[tid] = tmp[tid] - tcount[tid];
        if (tid == NBIN_PAD - 1) totalsh = tmp[NBIN_PAD - 1];
        {
            int cct = tcount[tid];
            gbase[tid] = goff[tid] + (cct ? atomicAdd(&delta[tid], cct) : 0);
            tcur[tid] = tmp[tid] - cct;
        }
        __syncthreads();
        for (int j = tid; j < lim; j += 256) {
            int u = e0[base + j], v = e1[base + j];
            if (u != v) {
                int b1 = u >> BIN_SHIFT;
                int s1 = atomicAdd(&tcur[b1], 1);
                buf[s1] = ((unsigned long long)b1 << 32) |
                          (unsigned)(((u & (BIN_SIZE - 1)) << 19) | v);
                int b2 = v >> BIN_SHIFT;
                int s2 = atomicAdd(&tcur[b2], 1);
                buf[s2] = ((unsigned long long)b2 << 32) |
                          (unsigned)(((v & (BIN_SIZE - 1)) << 19) | u);
            }
        }
        __syncthreads();
        int total = totalsh;
        for (int t = tid; t < total; t += 256) {
            unsigned long long e = buf[t];
            int b = (int)(e >> 32);
            binned[gbase[b] + (t - toff[b])] = (unsigned)e;
        }
        __syncthreads();
    }
}

__global__ __launch_bounds__(256)
void process_kernel(const unsigned* __restrict__ binned, const int* __restrict__ counts,
                    int* __restrict__ min1, int* __restrict__ min2, int n) {
    __shared__ int m1s[BIN_SIZE], m2s[BIN_SIZE];   // 16 KB
    __shared__ int tmp[NBIN_PAD];
    __shared__ int s_sh, e_sh;
    int tid = threadIdx.x, b = blockIdx.x;
    int c = counts[tid];
    tmp[tid] = c;
    __syncthreads();
    for (int off = 1; off < NBIN_PAD; off <<= 1) {
        int v = (tid >= off) ? tmp[tid - off] : 0;
        __syncthreads();
        tmp[tid] += v;
        __syncthreads();
    }
    if (tid == b) { e_sh = tmp[tid]; s_sh = tmp[tid] - c; }
    for (int i = tid; i < BIN_SIZE; i += 256) { m1s[i] = n; m2s[i] = n; }
    __syncthreads();
    int s = s_sh, e = e_sh;
    for (int j = s + tid; j < e; j += 256) {
        unsigned p = binned[j];
        atomicMin(&m1s[p >> 19], (int)(p & 0x7FFFFu));
    }
    __syncthreads();
    for (int j = s + tid; j < e; j += 256) {
        unsigned p = binned[j];
        int lu = p >> 19, v = (int)(p & 0x7FFFFu);
        if (v != m1s[lu]) atomicMin(&m2s[lu], v);
    }
    __syncthreads();
    int gb = b << BIN_SHIFT;
    for (int i = tid; i < BIN_SIZE; i += 256) {
        int g = gb + i;
        if (g < n) { min1[g] = m1s[i]; min2[g] = m2s[i]; }
    }
}

// ---------------- device-scope fallback ----------------
__global__ void init_min12(int* __restrict__ min1, int* __restrict__ min2, int n) {
    int i = blockIdx.x * blockDim.x + threadIdx.x;
    if (i < n) { min1[i] = n; min2[i] = n; }
}

__device__ __forceinline__ void upd_min1(int u, int v, int* __restrict__ min1) {
    if (u != v) {
        if (v < min1[u]) atomicMin(&min1[u], v);
        if (u < min1[v]) atomicMin(&min1[v], u);
    }
}

__global__ void edge_min1_kernel(const int* __restrict__ e0, const int* __restrict__ e1,
                                 int* __restrict__ min1, int m) {
    int t = blockIdx.x * blockDim.x + threadIdx.x;
    int base = t * 4;
    if (base >= m) return;
    if (base + 4 <= m) {
        int4 u4 = *(const int4*)(e0 + base);
        int4 v4 = *(const int4*)(e1 + base);
        upd_min1(u4.x, v4.x, min1);
        upd_min1(u4.y, v4.y, min1);
        upd_min1(u4.z, v4.z, min1);
        upd_min1(u4.w, v4.w, min1);
    } else {
        for (int j = base; j < m; j++) upd_min1(e0[j], e1[j], min1);
    }
}

__device__ __forceinline__ void upd_min2(int u, int v, const int* __restrict__ min1,
                                         int* __restrict__ min2) {
    if (u != v) {
        if (v != min1[u] && v < min2[u]) atomicMin(&min2[u], v);
        if (u != min1[v] && u < min2[v]) atomicMin(&min2[v], u);
    }
}

__global__ void edge_min2_kernel(const int* __restrict__ e0, const int* __restrict__ e1,
                                 const int* __restrict__ min1, int* __restrict__ min2, int m) {
    int t = blockIdx.x * blockDim.x + threadIdx.x;
    int base = t * 4;
    if (base >= m) return;
    if (base + 4 <= m) {
        int4 u4 = *(const int4*)(e0 + base);
        int4 v4 = *(const int4*)(e1 + base);
        upd_min2(u4.x, v4.x, min1, min2);
        upd_min2(u4.y, v4.y, min1, min2);
        upd_min2(u4.z, v4.z, min1, min2);
        upd_min2(u4.w, v4.w, min1, min2);
    } else {
        for (int j = base; j < m; j++) upd_min2(e0[j], e1[j], min1, min2);
    }
}

// ---------------- standalone feature bf16 prep ----------------
__global__ void prep_feat(const float* __restrict__ f, short* __restrict__ fb, long total) {
    long t = (long)blockIdx.x * blockDim.x + threadIdx.x;
    long base = t * 8;
    if (base >= total) return;
    float4 a = *(const float4*)(f + base);
    float4 b = *(const float4*)(f + base + 4);
    bf16x8 o;
    o[0] = f2bf(a.x); o[1] = f2bf(a.y); o[2] = f2bf(a.z); o[3] = f2bf(a.w);
    o[4] = f2bf(b.x); o[5] = f2bf(b.y); o[6] = f2bf(b.z); o[7] = f2bf(b.w);
    *(bf16x8*)(fb + base) = o;
}

// ---------------- fused node + feature-update kernel (2 m-tiles/wave, early update loads) ----------------
template<bool BF>
__global__ __launch_bounds__(256)
void node_kernel(const float* __restrict__ feat, const short* __restrict__ featbf,
                 const float* __restrict__ radii,
                 const float* __restrict__ b1rc, const float* __restrict__ b2rc,
                 const float* __restrict__ w3rc, const float* __restrict__ b3rc,
                 const float* __restrict__ b1cp, const float* __restrict__ b2cp,
                 const short* __restrict__ wt1t, const short* __restrict__ wt2t,
                 const int* __restrict__ types,
                 const int* __restrict__ min1, const int* __restrict__ min2,
                 float* __restrict__ out, float4* __restrict__ partials,
                 int n) {
    // No __syncthreads: each wave touches ONLY its own 32-node slice of LDS.
    __shared__ __align__(16) char Hbuf[BLK_NODES * H_ROWB];
    __shared__ float corrArr[BLK_NODES];
    __shared__ float zArr[BLK_NODES];
    __shared__ float gateArr[BLK_NODES];

    int tid = threadIdx.x;
    int blk = blockIdx.x;
    int lane = tid & 63;
    int w = tid >> 6;
    int lm = lane & 15;
    int lg = lane >> 4;
    int wnb = w * 32;

    int nid[2][3];
#pragma unroll
    for (int mt = 0; mt < 2; mt++) {
        int g = blk * BLK_NODES + wnb + mt * 16 + lm;
        int ii = (g < n) ? g : (n - 1);
        int m1 = min1[ii];
        int m2 = min2[ii];
        nid[mt][0] = ii;
        nid[mt][1] = (m1 < n) ? m1 : (n - 1);
        nid[mt][2] = (m2 < n) ? m2 : (n - 1);
    }

    // ---- EARLY update-stream loads: wave's own contiguous 8 KB of feat (independent) ----
    size_t wbase = (size_t)(blk * BLK_NODES + wnb) * F;
    const float* fsrc = feat + wbase;
    float4 updv[8];
#pragma unroll
    for (int q = 0; q < 8; q++) {
        int elem = q * 256 + lane * 4;
        int g = blk * BLK_NODES + wnb + (elem >> 6);
        updv[q] = (g < n) ? *(const float4*)(fsrc + elem)
                          : (float4){0.f, 0.f, 0.f, 0.f};
    }

    // ---- early epilogue prefetch (lanes 32-63 mirror 0-31) ----
    int el = lane & 31;
    int eg = blk * BLK_NODES + wnb + el;
    bool elive = eg < n;
    int eii = elive ? eg : (n - 1);
    int em1 = min1[eii];
    int em2 = min2[eii];
    float er0 = radii[eii];
    int ety = types[eii];
    int ec1 = (em1 < n) ? em1 : (n - 1);
    int ec2 = (em2 < n) ? em2 : (n - 1);
    float er1 = radii[ec1];
    float er2 = radii[ec2];

    bf16x8 af[2][3][2];
    if constexpr (BF) {
#pragma unroll
        for (int mt = 0; mt < 2; mt++)
#pragma unroll
            for (int part = 0; part < 3; part++)
#pragma unroll
                for (int h = 0; h < 2; h++)
                    af[mt][part][h] = *(const bf16x8*)(featbf + (size_t)nid[mt][part] * F + h * 32 + lg * 8);
    }

    f32x4 zero4 = {0.f, 0.f, 0.f, 0.f};
    f32x4 acc[2][8];
#pragma unroll
    for (int mt = 0; mt < 2; mt++)
#pragma unroll
        for (int nt = 0; nt < 8; nt++) acc[mt][nt] = zero4;

#pragma unroll
    for (int s = 0; s < 6; s++) {
        int part = s >> 1;
        int h = s & 1;
        bf16x8 a0, a1;
        if constexpr (BF) {
            a0 = af[0][part][h];
            a1 = af[1][part][h];
        } else {
#pragma unroll
            for (int mt = 0; mt < 2; mt++) {
                const float* rp = feat + (size_t)nid[mt][part] * F + h * 32 + lg * 8;
                float4 f0 = *(const float4*)rp;
                float4 f1 = *(const float4*)(rp + 4);
                bf16x8 a;
                a[0] = f2bf(f0.x); a[1] = f2bf(f0.y); a[2] = f2bf(f0.z); a[3] = f2bf(f0.w);
                a[4] = f2bf(f1.x); a[5] = f2bf(f1.y); a[6] = f2bf(f1.z); a[7] = f2bf(f1.w);
                if (mt == 0) a0 = a; else a1 = a;
            }
        }
#pragma unroll
        for (int nt = 0; nt < 8; nt++) {
            bf16x8 b = *(const bf16x8*)(wt1t + (lm + 16 * nt) * 192 + s * 32 + lg * 8);
            acc[0][nt] = __builtin_amdgcn_mfma_f32_16x16x32_bf16(a0, b, acc[0][nt], 0, 0, 0);
            acc[1][nt] = __builtin_amdgcn_mfma_f32_16x16x32_bf16(a1, b, acc[1][nt], 0, 0, 0);
        }
    }

    float b1v[8];
#pragma unroll
    for (int nt = 0; nt < 8; nt++)
        b1v[nt] = (nt < 4) ? b1rc[lm + 16 * nt] : b1cp[lm + 16 * nt - 64];

#pragma unroll
    for (int mt = 0; mt < 2; mt++) {
#pragma unroll
        for (int r = 0; r < 4; r++) {
            int node = wnb + mt * 16 + lg * 4 + r;
            bf16x8 hv;
#pragma unroll
            for (int nt = 0; nt < 8; nt++)
                hv[nt] = f2bf(fmaxf(acc[mt][nt][r] + b1v[nt], 0.f));
            *(bf16x8*)(Hbuf + node * H_ROWB + lm * 16) = hv;
        }
    }

    f32x4 acc2[2][3];
#pragma unroll
    for (int mt = 0; mt < 2; mt++)
#pragma unroll
        for (int nt = 0; nt < 3; nt++) acc2[mt][nt] = zero4;

#pragma unroll
    for (int s = 0; s < 4; s++) {
        bf16x8 af2[2];
#pragma unroll
        for (int mt = 0; mt < 2; mt++)
            af2[mt] = *(const bf16x8*)(Hbuf + (wnb + mt * 16 + lm) * H_ROWB + s * 64 + lg * 16);
#pragma unroll
        for (int nt = 0; nt < 3; nt++) {
            bf16x8 b = *(const bf16x8*)(wt2t + (lm + 16 * nt) * 128 + s * 32 + lg * 8);
            acc2[0][nt] = __builtin_amdgcn_mfma_f32_16x16x32_bf16(af2[0], b, acc2[0][nt], 0, 0, 0);
            acc2[1][nt] = __builtin_amdgcn_mfma_f32_16x16x32_bf16(af2[1], b, acc2[1][nt], 0, 0, 0);
        }
    }

#pragma unroll
    for (int mt = 0; mt < 2; mt++) {
#pragma unroll
        for (int r = 0; r < 4; r++) {
            float t = 0.f;
#pragma unroll
            for (int nt = 0; nt < 2; nt++) {
                int o = lm + 16 * nt;
                float s2v = fmaxf(acc2[mt][nt][r] + b2rc[o], 0.f);
                t = fmaf(s2v, w3rc[o], t);
            }
            float zz = acc2[mt][2][r];
#pragma unroll
            for (int msk = 1; msk < 16; msk <<= 1) {
                t  += __shfl_xor(t, msk);
                zz += __shfl_xor(zz, msk);
            }
            if (lm == 0) {
                int node = wnb + mt * 16 + lg * 4 + r;
                corrArr[node] = t + b3rc[0];
                zArr[node]    = zz + b2cp[0];
            }
        }
    }

    // ---------- per-wave epilogue (prefetched values) ----------
    float sv = 0.f, sc = 0.f, ct = 0.f;
    if (lane < 32) {
        bool valid = em2 < n;
        float pr3 = er0 * er0 * er0;
        float viol = fabsf(er1 * er1 * er1 + er2 * er2 * er2 - pr3) / pr3;
        bool active = elive && valid && (ety == 1);
        bool upd = active && (viol > VIOL_THRESH);
        float gate = upd ? corrArr[wnb + el] : 0.f;
        gateArr[wnb + el] = 0.1f * gate;
        if (active) {
            sv = viol;
            sc = fast_sigmoid(zArr[wnb + el]);
            ct = 1.f;
        }
    }
#pragma unroll
    for (int off = 32; off > 0; off >>= 1) {
        sv += __shfl_down(sv, off);
        sc += __shfl_down(sc, off);
        ct += __shfl_down(ct, off);
    }
    if (lane == 0) {
        float4 p; p.x = sv; p.y = sc; p.z = ct; p.w = 0.f;
        partials[blk * 4 + w] = p;
    }

    // ---------- feature update: data already in registers, stores fire-and-forget ----------
    {
        float* fdst = out + wbase;
#pragma unroll
        for (int q = 0; q < 8; q++) {
            int elem = q * 256 + lane * 4;
            int nloc = wnb + (elem >> 6);
            int g = blk * BLK_NODES + nloc;
            if (g < n) {
                float gate01 = gateArr[nloc];
                float4 v = updv[q];
                float4 r;
                r.x = v.x + gate01 * fast_tanh(v.x);
                r.y = v.y + gate01 * fast_tanh(v.y);
                r.z = v.z + gate01 * fast_tanh(v.z);
                r.w = v.w + gate01 * fast_tanh(v.w);
                *(float4*)(fdst + elem) = r;
            }
        }
    }
}

__global__ __launch_bounds__(256)
void finalize_kernel(const float4* __restrict__ partials, int np,
                     float* __restrict__ out_scalars) {
    __shared__ float red[3][4];
    int tid = threadIdx.x;
    float sv = 0.f, sc = 0.f, ct = 0.f;
    for (int i = tid; i < np; i += 256) {
        float4 p = partials[i];
        sv += p.x; sc += p.y; ct += p.z;
    }
#pragma unroll
    for (int off = 32; off > 0; off >>= 1) {
        sv += __shfl_down(sv, off);
        sc += __shfl_down(sc, off);
        ct += __shfl_down(ct, off);
    }
    int lane = tid & 63, w = tid >> 6;
    if (lane == 0) { red[0][w] = sv; red[1][w] = sc; red[2][w] = ct; }
    __syncthreads();
    if (tid == 0) {
        float tv = red[0][0] + red[0][1] + red[0][2] + red[0][3];
        float tc = red[1][0] + red[1][1] + red[1][2] + red[1][3];
        float tn = red[2][0] + red[2][1] + red[2][2] + red[2][3];
        float d = tn > 1.f ? tn : 1.f;
        out_scalars[0] = tv / d;
        out_scalars[1] = tc / d;
    }
}

extern "C" void kernel_launch(void* const* d_in, const int* in_sizes, int n_in,
                              void* d_out, int out_size, void* d_ws, size_t ws_size,
                              hipStream_t stream) {
    const float* feat  = (const float*)d_in[0];
    const float* radii = (const float*)d_in[1];
    const float* w1rc  = (const float*)d_in[2];
    const float* b1rc  = (const float*)d_in[3];
    const float* w2rc  = (const float*)d_in[4];
    const float* b2rc  = (const float*)d_in[5];
    const float* w3rc  = (const float*)d_in[6];
    const float* b3rc  = (const float*)d_in[7];
    const float* w1cp  = (const float*)d_in[8];
    const float* b1cp  = (const float*)d_in[9];
    const float* w2cp  = (const float*)d_in[10];
    const float* b2cp  = (const float*)d_in[11];
    const int*   eidx  = (const int*)d_in[12];
    const int*   types = (const int*)d_in[13];

    int n = in_sizes[0] / F;          // 300000
    int m = in_sizes[12] / 2;         // 3000000

    int nblocks = (n + BLK_NODES - 1) / BLK_NODES;
    int np = nblocks * 4;
    int nbins = (n + BIN_SIZE - 1) >> BIN_SHIFT;

    // ws layout: wt1t | wt2t | min1 | min2 | partials | counts | delta | [binned][featbf]
    char* ws = (char*)d_ws;
    short* wt1t = (short*)ws;                            ws += 128 * 192 * 2;
    short* wt2t = (short*)ws;                            ws += 48 * 128 * 2;
    int* min1 = (int*)ws;                                ws += (size_t)n * 4;
    int* min2 = (int*)ws;                                ws += (size_t)n * 4;
    float4* partials = (float4*)ws;                      ws += (size_t)np * 16;
    int* counts = (int*)ws;                              ws += NBIN_PAD * 4;
    int* delta  = (int*)ws;                              ws += NBIN_PAD * 4;

    size_t used = (size_t)(ws - (char*)d_ws);
    size_t binned_bytes = (size_t)2 * m * 4;
    size_t featbf_bytes = (size_t)n * F * 2;

    bool useBinned = (n < (1 << 19)) && (nbins <= NBIN_PAD) && (used + binned_bytes <= ws_size);
    bool sepBuf    = useBinned && (used + binned_bytes + featbf_bytes <= ws_size);
    unsigned* binned = (unsigned*)ws;
    short* featbf;
    bool useBF;
    if (sepBuf) {
        featbf = (short*)(ws + binned_bytes);
        useBF = true;
    } else {
        featbf = (short*)ws;   // overlays binned (sequential use)
        useBF = (used + featbf_bytes) <= ws_size;
    }

    float* out         = (float*)d_out;
    float* out_scalars = out + (size_t)n * F;

    int bs = 256;
    const int* e0 = eidx;
    const int* e1 = eidx + m;
    long total = (long)n * F;
    long prepthr = total / 8;
    int prepblocks = (int)((prepthr + bs - 1) / bs);

    // -------- setup (zero counts/delta + weight transposes) --------
    setup_kernel<<<121, bs, 0, stream>>>(counts, delta, w1rc, w1cp, wt1t, w2rc, w2cp, wt2t);

    // -------- edge phase --------
    if (useBinned) {
        if (sepBuf && useBF) {
            count_prep_kernel<<<1024 + prepblocks, bs, 0, stream>>>(
                e0, e1, counts, m, feat, featbf, total, 1024);
        } else {
            count_prep_kernel<<<1024, bs, 0, stream>>>(
                e0, e1, counts, m, feat, featbf, 0, 1024);
        }
        scatter_kernel<<<768, bs, 0, stream>>>(e0, e1, counts, delta, binned, m);
        process_kernel<<<nbins, bs, 0, stream>>>(binned, counts, min1, min2, n);
        if (!sepBuf && useBF)
            prep_feat<<<prepblocks, bs, 0, stream>>>(feat, featbf, total);
    } else {
        int mt4 = (m + 3) / 4;
        init_min12<<<(n + bs - 1) / bs, bs, 0, stream>>>(min1, min2, n);
        edge_min1_kernel<<<(mt4 + bs - 1) / bs, bs, 0, stream>>>(e0, e1, min1, m);
        edge_min2_kernel<<<(mt4 + bs - 1) / bs, bs, 0, stream>>>(e0, e1, min1, min2, m);
        if (useBF)
            prep_feat<<<prepblocks, bs, 0, stream>>>(feat, featbf, total);
    }

    // -------- fused node + update --------
    if (useBF) {
        node_kernel<true><<<nblocks, bs, 0, stream>>>(
            feat, featbf, radii, b1rc, b2rc, w3rc, b3rc, b1cp, b2cp,
            wt1t, wt2t, types, min1, min2, out, partials, n);
    } else {
        node_kernel<false><<<nblocks, bs, 0, stream>>>(
            feat, featbf, radii, b1rc, b2rc, w3rc, b3rc, b1cp, b2cp,
            wt1t, wt2t, types, min1, min2, out, partials, n);
    }
    finalize_kernel<<<1, 256, 0, stream>>>(partials, np, out_scalars);
}

// Round 16
// 254.925 us; speedup vs baseline: 1.3093x; 1.1115x over previous
//
#include <hip/hip_runtime.h>
#include <math.h>

#define F 64
#define VIOL_THRESH 0.2f
#define BLK_NODES 128
#define H_ROWB 272   // 136 bf16 per row: 68 words ≡ 4 mod 32 banks -> 2-way (free)
#define BIN_SHIFT 11
#define BIN_SIZE 2048
#define NBIN_PAD 256
#define TILE 2048

typedef float  f32x4  __attribute__((ext_vector_type(4)));
typedef short  bf16x8 __attribute__((ext_vector_type(8)));

__device__ __forceinline__ short f2bf(float f) {
    unsigned u = __builtin_bit_cast(unsigned, f);
    unsigned r = (u + 0x7fffu + ((u >> 16) & 1u)) >> 16;
    return (short)r;
}

__device__ __forceinline__ float fexp2(float x) {
#if __has_builtin(__builtin_amdgcn_exp2f)
    return __builtin_amdgcn_exp2f(x);
#else
    return exp2f(x);
#endif
}

__device__ __forceinline__ float frcp(float x) {
#if __has_builtin(__builtin_amdgcn_rcpf)
    return __builtin_amdgcn_rcpf(x);
#else
    return 1.0f / x;
#endif
}

__device__ __forceinline__ float fast_tanh(float x) {
    float xc = fminf(fmaxf(x, -9.0f), 9.0f);
    float e = fexp2(xc * 2.885390081777927f);
    return (e - 1.0f) * frcp(e + 1.0f);
}

__device__ __forceinline__ float fast_sigmoid(float z) {
    return frcp(1.0f + fexp2(-z * 1.4426950408889634f));
}

// ---------------- fused setup: zero counts/delta + weight transposes ----------------
__global__ __launch_bounds__(256)
void setup_kernel(int* __restrict__ counts, int* __restrict__ delta,
                  const float* __restrict__ w1rc, const float* __restrict__ w1cp,
                  short* __restrict__ wt1t,
                  const float* __restrict__ w2rc, const float* __restrict__ w2cp,
                  short* __restrict__ wt2t) {
    int b = blockIdx.x, tid = threadIdx.x;
    if (b == 0) { counts[tid] = 0; delta[tid] = 0; return; }
    b -= 1;
    if (b < 24) {                      // wt2t: 48*128 = 6144 elems
        int e = b * 256 + tid;
        int o = e >> 7, k = e & 127;
        float v = 0.f;
        if (o < 32)       { if (k < 64) v = w2rc[k * 32 + o]; }
        else if (o == 32) { if (k >= 64) v = w2cp[k - 64]; }
        int kp = (k & 15) * 8 + (k >> 4);
        wt2t[o * 128 + kp] = f2bf(v);
        return;
    }
    b -= 24;
    {                                  // wt1t: 128*192 = 24576 elems
        int e = b * 256 + tid;
        int o = e / 192, k = e % 192;
        const float* src = (o < 64) ? (w1rc + o) : (w1cp + (o - 64));
        wt1t[o * 192 + k] = f2bf(src[(size_t)k * 64]);
    }
}

// ---------------- FIXED-CAPACITY scatter (no count pass) + fused feat prep ----------------
__global__ __launch_bounds__(256)
void scatter_fixed_kernel(const int* __restrict__ e0, const int* __restrict__ e1,
                          int* __restrict__ delta, unsigned* __restrict__ binned,
                          int m, int cap, int sblocks,
                          const float* __restrict__ feat, short* __restrict__ featbf,
                          long total) {
    int tid = threadIdx.x;
    if ((int)blockIdx.x >= sblocks) {
        // feature bf16 prep blocks
        long t = (long)((int)blockIdx.x - sblocks) * 256 + tid;
        long base = t * 8;
        if (base >= total) return;
        float4 a = *(const float4*)(feat + base);
        float4 b = *(const float4*)(feat + base + 4);
        bf16x8 o;
        o[0] = f2bf(a.x); o[1] = f2bf(a.y); o[2] = f2bf(a.z); o[3] = f2bf(a.w);
        o[4] = f2bf(b.x); o[5] = f2bf(b.y); o[6] = f2bf(b.z); o[7] = f2bf(b.w);
        *(bf16x8*)(featbf + base) = o;
        return;
    }
    __shared__ unsigned long long buf[2 * TILE];          // 32 KB
    __shared__ int tcount[NBIN_PAD], toff[NBIN_PAD], tmp[NBIN_PAD];
    __shared__ int gbase[NBIN_PAD], tcur[NBIN_PAD];
    __shared__ int totalsh;

    int ntile = (m + TILE - 1) / TILE;
    for (int tile = blockIdx.x; tile < ntile; tile += sblocks) {
        int base = tile * TILE;
        int lim = min(TILE, m - base);
        tcount[tid] = 0;
        __syncthreads();
        for (int j = tid; j < lim; j += 256) {
            int u = e0[base + j], v = e1[base + j];
            if (u != v) {
                atomicAdd(&tcount[u >> BIN_SHIFT], 1);
                atomicAdd(&tcount[v >> BIN_SHIFT], 1);
            }
        }
        __syncthreads();
        tmp[tid] = tcount[tid];
        __syncthreads();
        for (int off = 1; off < NBIN_PAD; off <<= 1) {
            int vv = (tid >= off) ? tmp[tid - off] : 0;
            __syncthreads();
            tmp[tid] += vv;
            __syncthreads();
        }
        toff[tid] = tmp[tid] - tcount[tid];
        if (tid == NBIN_PAD - 1) totalsh = tmp[NBIN_PAD - 1];
        {
            int cct = tcount[tid];
            gbase[tid] = tid * cap + (cct ? atomicAdd(&delta[tid], cct) : 0);
            tcur[tid] = tmp[tid] - cct;
        }
        __syncthreads();
        for (int j = tid; j < lim; j += 256) {
            int u = e0[base + j], v = e1[base + j];
            if (u != v) {
                int b1 = u >> BIN_SHIFT;
                int s1 = atomicAdd(&tcur[b1], 1);
                buf[s1] = ((unsigned long long)b1 << 32) |
                          (unsigned)(((u & (BIN_SIZE - 1)) << 19) | v);
                int b2 = v >> BIN_SHIFT;
                int s2 = atomicAdd(&tcur[b2], 1);
                buf[s2] = ((unsigned long long)b2 << 32) |
                          (unsigned)(((v & (BIN_SIZE - 1)) << 19) | u);
            }
        }
        __syncthreads();
        int total_t = totalsh;
        for (int t = tid; t < total_t; t += 256) {
            unsigned long long e = buf[t];
            int b = (int)(e >> 32);
            binned[gbase[b] + (t - toff[b])] = (unsigned)e;
        }
        __syncthreads();
    }
}

__global__ __launch_bounds__(256)
void process_fixed_kernel(const unsigned* __restrict__ binned, const int* __restrict__ delta,
                          int* __restrict__ min1, int* __restrict__ min2, int n, int cap) {
    __shared__ int m1s[BIN_SIZE], m2s[BIN_SIZE];   // 16 KB
    int tid = threadIdx.x, b = blockIdx.x;
    int cnt = min(delta[b], cap);
    for (int i = tid; i < BIN_SIZE; i += 256) { m1s[i] = n; m2s[i] = n; }
    __syncthreads();
    long s = (long)b * cap;
    long e = s + cnt;
    for (long j = s + tid; j < e; j += 256) {
        unsigned p = binned[j];
        atomicMin(&m1s[p >> 19], (int)(p & 0x7FFFFu));
    }
    __syncthreads();
    for (long j = s + tid; j < e; j += 256) {
        unsigned p = binned[j];
        int lu = p >> 19, v = (int)(p & 0x7FFFFu);
        if (v != m1s[lu]) atomicMin(&m2s[lu], v);
    }
    __syncthreads();
    int gb = b << BIN_SHIFT;
    for (int i = tid; i < BIN_SIZE; i += 256) {
        int g = gb + i;
        if (g < n) { min1[g] = m1s[i]; min2[g] = m2s[i]; }
    }
}

// ---------------- compact-binned fallback (count + scan) ----------------
__global__ __launch_bounds__(256)
void count_prep_kernel(const int* __restrict__ e0, const int* __restrict__ e1,
                       int* __restrict__ counts, int m,
                       const float* __restrict__ feat, short* __restrict__ featbf,
                       long total, int cblocks) {
    int tid = threadIdx.x;
    if ((int)blockIdx.x < cblocks) {
        __shared__ int c[NBIN_PAD];
        c[tid] = 0;
        __syncthreads();
        for (long j = (long)blockIdx.x * 256 + tid; j < m; j += (long)cblocks * 256) {
            int u = e0[j], v = e1[j];
            if (u != v) {
                atomicAdd(&c[u >> BIN_SHIFT], 1);
                atomicAdd(&c[v >> BIN_SHIFT], 1);
            }
        }
        __syncthreads();
        if (c[tid]) atomicAdd(&counts[tid], c[tid]);
    } else {
        long t = (long)((int)blockIdx.x - cblocks) * 256 + tid;
        long base = t * 8;
        if (base >= total) return;
        float4 a = *(const float4*)(feat + base);
        float4 b = *(const float4*)(feat + base + 4);
        bf16x8 o;
        o[0] = f2bf(a.x); o[1] = f2bf(a.y); o[2] = f2bf(a.z); o[3] = f2bf(a.w);
        o[4] = f2bf(b.x); o[5] = f2bf(b.y); o[6] = f2bf(b.z); o[7] = f2bf(b.w);
        *(bf16x8*)(featbf + base) = o;
    }
}

__global__ __launch_bounds__(256)
void scatter_kernel(const int* __restrict__ e0, const int* __restrict__ e1,
                    const int* __restrict__ counts, int* __restrict__ delta,
                    unsigned* __restrict__ binned, int m) {
    __shared__ unsigned long long buf[2 * TILE];
    __shared__ int goff[NBIN_PAD];
    __shared__ int tcount[NBIN_PAD], toff[NBIN_PAD], tmp[NBIN_PAD];
    __shared__ int gbase[NBIN_PAD], tcur[NBIN_PAD];
    __shared__ int totalsh;
    int tid = threadIdx.x;

    int c = counts[tid];
    tmp[tid] = c;
    __syncthreads();
    for (int off = 1; off < NBIN_PAD; off <<= 1) {
        int v = (tid >= off) ? tmp[tid - off] : 0;
        __syncthreads();
        tmp[tid] += v;
        __syncthreads();
    }
    goff[tid] = tmp[tid] - c;
    __syncthreads();

    int ntile = (m + TILE - 1) / TILE;
    for (int tile = blockIdx.x; tile < ntile; tile += gridDim.x) {
        int base = tile * TILE;
        int lim = min(TILE, m - base);
        tcount[tid] = 0;
        __syncthreads();
        for (int j = tid; j < lim; j += 256) {
            int u = e0[base + j], v = e1[base + j];
            if (u != v) {
                atomicAdd(&tcount[u >> BIN_SHIFT], 1);
                atomicAdd(&tcount[v >> BIN_SHIFT], 1);
            }
        }
        __syncthreads();
        tmp[tid] = tcount[tid];
        __syncthreads();
        for (int off = 1; off < NBIN_PAD; off <<= 1) {
            int vv = (tid >= off) ? tmp[tid - off] : 0;
            __syncthreads();
            tmp[tid] += vv;
            __syncthreads();
        }
        toff[tid] = tmp[tid] - tcount[tid];
        if (tid == NBIN_PAD - 1) totalsh = tmp[NBIN_PAD - 1];
        {
            int cct = tcount[tid];
            gbase[tid] = goff[tid] + (cct ? atomicAdd(&delta[tid], cct) : 0);
            tcur[tid] = tmp[tid] - cct;
        }
        __syncthreads();
        for (int j = tid; j < lim; j += 256) {
            int u = e0[base + j], v = e1[base + j];
            if (u != v) {
                int b1 = u >> BIN_SHIFT;
                int s1 = atomicAdd(&tcur[b1], 1);
                buf[s1] = ((unsigned long long)b1 << 32) |
                          (unsigned)(((u & (BIN_SIZE - 1)) << 19) | v);
                int b2 = v >> BIN_SHIFT;
                int s2 = atomicAdd(&tcur[b2], 1);
                buf[s2] = ((unsigned long long)b2 << 32) |
                          (unsigned)(((v & (BIN_SIZE - 1)) << 19) | u);
            }
        }
        __syncthreads();
        int total = totalsh;
        for (int t = tid; t < total; t += 256) {
            unsigned long long e = buf[t];
            int b = (int)(e >> 32);
            binned[gbase[b] + (t - toff[b])] = (unsigned)e;
        }
        __syncthreads();
    }
}

__global__ __launch_bounds__(256)
void process_kernel(const unsigned* __restrict__ binned, const int* __restrict__ counts,
                    int* __restrict__ min1, int* __restrict__ min2, int n) {
    __shared__ int m1s[BIN_SIZE], m2s[BIN_SIZE];
    __shared__ int tmp[NBIN_PAD];
    __shared__ int s_sh, e_sh;
    int tid = threadIdx.x, b = blockIdx.x;
    int c = counts[tid];
    tmp[tid] = c;
    __syncthreads();
    for (int off = 1; off < NBIN_PAD; off <<= 1) {
        int v = (tid >= off) ? tmp[tid - off] : 0;
        __syncthreads();
        tmp[tid] += v;
        __syncthreads();
    }
    if (tid == b) { e_sh = tmp[tid]; s_sh = tmp[tid] - c; }
    for (int i = tid; i < BIN_SIZE; i += 256) { m1s[i] = n; m2s[i] = n; }
    __syncthreads();
    int s = s_sh, e = e_sh;
    for (int j = s + tid; j < e; j += 256) {
        unsigned p = binned[j];
        atomicMin(&m1s[p >> 19], (int)(p & 0x7FFFFu));
    }
    __syncthreads();
    for (int j = s + tid; j < e; j += 256) {
        unsigned p = binned[j];
        int lu = p >> 19, v = (int)(p & 0x7FFFFu);
        if (v != m1s[lu]) atomicMin(&m2s[lu], v);
    }
    __syncthreads();
    int gb = b << BIN_SHIFT;
    for (int i = tid; i < BIN_SIZE; i += 256) {
        int g = gb + i;
        if (g < n) { min1[g] = m1s[i]; min2[g] = m2s[i]; }
    }
}

// ---------------- device-scope fallback ----------------
__global__ void init_min12(int* __restrict__ min1, int* __restrict__ min2, int n) {
    int i = blockIdx.x * blockDim.x + threadIdx.x;
    if (i < n) { min1[i] = n; min2[i] = n; }
}

__device__ __forceinline__ void upd_min1(int u, int v, int* __restrict__ min1) {
    if (u != v) {
        if (v < min1[u]) atomicMin(&min1[u], v);
        if (u < min1[v]) atomicMin(&min1[v], u);
    }
}

__global__ void edge_min1_kernel(const int* __restrict__ e0, const int* __restrict__ e1,
                                 int* __restrict__ min1, int m) {
    int t = blockIdx.x * blockDim.x + threadIdx.x;
    int base = t * 4;
    if (base >= m) return;
    if (base + 4 <= m) {
        int4 u4 = *(const int4*)(e0 + base);
        int4 v4 = *(const int4*)(e1 + base);
        upd_min1(u4.x, v4.x, min1);
        upd_min1(u4.y, v4.y, min1);
        upd_min1(u4.z, v4.z, min1);
        upd_min1(u4.w, v4.w, min1);
    } else {
        for (int j = base; j < m; j++) upd_min1(e0[j], e1[j], min1);
    }
}

__device__ __forceinline__ void upd_min2(int u, int v, const int* __restrict__ min1,
                                         int* __restrict__ min2) {
    if (u != v) {
        if (v != min1[u] && v < min2[u]) atomicMin(&min2[u], v);
        if (u != min1[v] && u < min2[v]) atomicMin(&min2[v], u);
    }
}

__global__ void edge_min2_kernel(const int* __restrict__ e0, const int* __restrict__ e1,
                                 const int* __restrict__ min1, int* __restrict__ min2, int m) {
    int t = blockIdx.x * blockDim.x + threadIdx.x;
    int base = t * 4;
    if (base >= m) return;
    if (base + 4 <= m) {
        int4 u4 = *(const int4*)(e0 + base);
        int4 v4 = *(const int4*)(e1 + base);
        upd_min2(u4.x, v4.x, min1, min2);
        upd_min2(u4.y, v4.y, min1, min2);
        upd_min2(u4.z, v4.z, min1, min2);
        upd_min2(u4.w, v4.w, min1, min2);
    } else {
        for (int j = base; j < m; j++) upd_min2(e0[j], e1[j], min1, min2);
    }
}

// ---------------- standalone feature bf16 prep ----------------
__global__ void prep_feat(const float* __restrict__ f, short* __restrict__ fb, long total) {
    long t = (long)blockIdx.x * blockDim.x + threadIdx.x;
    long base = t * 8;
    if (base >= total) return;
    float4 a = *(const float4*)(f + base);
    float4 b = *(const float4*)(f + base + 4);
    bf16x8 o;
    o[0] = f2bf(a.x); o[1] = f2bf(a.y); o[2] = f2bf(a.z); o[3] = f2bf(a.w);
    o[4] = f2bf(b.x); o[5] = f2bf(b.y); o[6] = f2bf(b.z); o[7] = f2bf(b.w);
    *(bf16x8*)(fb + base) = o;
}

// ---------------- fused node + feature-update kernel (2 m-tiles/wave, early update loads) ----------------
template<bool BF>
__global__ __launch_bounds__(256)
void node_kernel(const float* __restrict__ feat, const short* __restrict__ featbf,
                 const float* __restrict__ radii,
                 const float* __restrict__ b1rc, const float* __restrict__ b2rc,
                 const float* __restrict__ w3rc, const float* __restrict__ b3rc,
                 const float* __restrict__ b1cp, const float* __restrict__ b2cp,
                 const short* __restrict__ wt1t, const short* __restrict__ wt2t,
                 const int* __restrict__ types,
                 const int* __restrict__ min1, const int* __restrict__ min2,
                 float* __restrict__ out, float4* __restrict__ partials,
                 int n) {
    __shared__ __align__(16) char Hbuf[BLK_NODES * H_ROWB];
    __shared__ float corrArr[BLK_NODES];
    __shared__ float zArr[BLK_NODES];
    __shared__ float gateArr[BLK_NODES];

    int tid = threadIdx.x;
    int blk = blockIdx.x;
    int lane = tid & 63;
    int w = tid >> 6;
    int lm = lane & 15;
    int lg = lane >> 4;
    int wnb = w * 32;

    int nid[2][3];
#pragma unroll
    for (int mt = 0; mt < 2; mt++) {
        int g = blk * BLK_NODES + wnb + mt * 16 + lm;
        int ii = (g < n) ? g : (n - 1);
        int m1 = min1[ii];
        int m2 = min2[ii];
        nid[mt][0] = ii;
        nid[mt][1] = (m1 < n) ? m1 : (n - 1);
        nid[mt][2] = (m2 < n) ? m2 : (n - 1);
    }

    // ---- EARLY update-stream loads ----
    size_t wbase = (size_t)(blk * BLK_NODES + wnb) * F;
    const float* fsrc = feat + wbase;
    float4 updv[8];
#pragma unroll
    for (int q = 0; q < 8; q++) {
        int elem = q * 256 + lane * 4;
        int g = blk * BLK_NODES + wnb + (elem >> 6);
        updv[q] = (g < n) ? *(const float4*)(fsrc + elem)
                          : (float4){0.f, 0.f, 0.f, 0.f};
    }

    // ---- early epilogue prefetch ----
    int el = lane & 31;
    int eg = blk * BLK_NODES + wnb + el;
    bool elive = eg < n;
    int eii = elive ? eg : (n - 1);
    int em1 = min1[eii];
    int em2 = min2[eii];
    float er0 = radii[eii];
    int ety = types[eii];
    int ec1 = (em1 < n) ? em1 : (n - 1);
    int ec2 = (em2 < n) ? em2 : (n - 1);
    float er1 = radii[ec1];
    float er2 = radii[ec2];

    bf16x8 af[2][3][2];
    if constexpr (BF) {
#pragma unroll
        for (int mt = 0; mt < 2; mt++)
#pragma unroll
            for (int part = 0; part < 3; part++)
#pragma unroll
                for (int h = 0; h < 2; h++)
                    af[mt][part][h] = *(const bf16x8*)(featbf + (size_t)nid[mt][part] * F + h * 32 + lg * 8);
    }

    f32x4 zero4 = {0.f, 0.f, 0.f, 0.f};
    f32x4 acc[2][8];
#pragma unroll
    for (int mt = 0; mt < 2; mt++)
#pragma unroll
        for (int nt = 0; nt < 8; nt++) acc[mt][nt] = zero4;

#pragma unroll
    for (int s = 0; s < 6; s++) {
        int part = s >> 1;
        int h = s & 1;
        bf16x8 a0, a1;
        if constexpr (BF) {
            a0 = af[0][part][h];
            a1 = af[1][part][h];
        } else {
#pragma unroll
            for (int mt = 0; mt < 2; mt++) {
                const float* rp = feat + (size_t)nid[mt][part] * F + h * 32 + lg * 8;
                float4 f0 = *(const float4*)rp;
                float4 f1 = *(const float4*)(rp + 4);
                bf16x8 a;
                a[0] = f2bf(f0.x); a[1] = f2bf(f0.y); a[2] = f2bf(f0.z); a[3] = f2bf(f0.w);
                a[4] = f2bf(f1.x); a[5] = f2bf(f1.y); a[6] = f2bf(f1.z); a[7] = f2bf(f1.w);
                if (mt == 0) a0 = a; else a1 = a;
            }
        }
#pragma unroll
        for (int nt = 0; nt < 8; nt++) {
            bf16x8 b = *(const bf16x8*)(wt1t + (lm + 16 * nt) * 192 + s * 32 + lg * 8);
            acc[0][nt] = __builtin_amdgcn_mfma_f32_16x16x32_bf16(a0, b, acc[0][nt], 0, 0, 0);
            acc[1][nt] = __builtin_amdgcn_mfma_f32_16x16x32_bf16(a1, b, acc[1][nt], 0, 0, 0);
        }
    }

    float b1v[8];
#pragma unroll
    for (int nt = 0; nt < 8; nt++)
        b1v[nt] = (nt < 4) ? b1rc[lm + 16 * nt] : b1cp[lm + 16 * nt - 64];

#pragma unroll
    for (int mt = 0; mt < 2; mt++) {
#pragma unroll
        for (int r = 0; r < 4; r++) {
            int node = wnb + mt * 16 + lg * 4 + r;
            bf16x8 hv;
#pragma unroll
            for (int nt = 0; nt < 8; nt++)
                hv[nt] = f2bf(fmaxf(acc[mt][nt][r] + b1v[nt], 0.f));
            *(bf16x8*)(Hbuf + node * H_ROWB + lm * 16) = hv;
        }
    }

    f32x4 acc2[2][3];
#pragma unroll
    for (int mt = 0; mt < 2; mt++)
#pragma unroll
        for (int nt = 0; nt < 3; nt++) acc2[mt][nt] = zero4;

#pragma unroll
    for (int s = 0; s < 4; s++) {
        bf16x8 af2[2];
#pragma unroll
        for (int mt = 0; mt < 2; mt++)
            af2[mt] = *(const bf16x8*)(Hbuf + (wnb + mt * 16 + lm) * H_ROWB + s * 64 + lg * 16);
#pragma unroll
        for (int nt = 0; nt < 3; nt++) {
            bf16x8 b = *(const bf16x8*)(wt2t + (lm + 16 * nt) * 128 + s * 32 + lg * 8);
            acc2[0][nt] = __builtin_amdgcn_mfma_f32_16x16x32_bf16(af2[0], b, acc2[0][nt], 0, 0, 0);
            acc2[1][nt] = __builtin_amdgcn_mfma_f32_16x16x32_bf16(af2[1], b, acc2[1][nt], 0, 0, 0);
        }
    }

#pragma unroll
    for (int mt = 0; mt < 2; mt++) {
#pragma unroll
        for (int r = 0; r < 4; r++) {
            float t = 0.f;
#pragma unroll
            for (int nt = 0; nt < 2; nt++) {
                int o = lm + 16 * nt;
                float s2v = fmaxf(acc2[mt][nt][r] + b2rc[o], 0.f);
                t = fmaf(s2v, w3rc[o], t);
            }
            float zz = acc2[mt][2][r];
#pragma unroll
            for (int msk = 1; msk < 16; msk <<= 1) {
                t  += __shfl_xor(t, msk);
                zz += __shfl_xor(zz, msk);
            }
            if (lm == 0) {
                int node = wnb + mt * 16 + lg * 4 + r;
                corrArr[node] = t + b3rc[0];
                zArr[node]    = zz + b2cp[0];
            }
        }
    }

    // ---------- per-wave epilogue ----------
    float sv = 0.f, sc = 0.f, ct = 0.f;
    if (lane < 32) {
        bool valid = em2 < n;
        float pr3 = er0 * er0 * er0;
        float viol = fabsf(er1 * er1 * er1 + er2 * er2 * er2 - pr3) / pr3;
        bool active = elive && valid && (ety == 1);
        bool upd = active && (viol > VIOL_THRESH);
        float gate = upd ? corrArr[wnb + el] : 0.f;
        gateArr[wnb + el] = 0.1f * gate;
        if (active) {
            sv = viol;
            sc = fast_sigmoid(zArr[wnb + el]);
            ct = 1.f;
        }
    }
#pragma unroll
    for (int off = 32; off > 0; off >>= 1) {
        sv += __shfl_down(sv, off);
        sc += __shfl_down(sc, off);
        ct += __shfl_down(ct, off);
    }
    if (lane == 0) {
        float4 p; p.x = sv; p.y = sc; p.z = ct; p.w = 0.f;
        partials[blk * 4 + w] = p;
    }

    // ---------- feature update (data in registers) ----------
    {
        float* fdst = out + wbase;
#pragma unroll
        for (int q = 0; q < 8; q++) {
            int elem = q * 256 + lane * 4;
            int nloc = wnb + (elem >> 6);
            int g = blk * BLK_NODES + nloc;
            if (g < n) {
                float gate01 = gateArr[nloc];
                float4 v = updv[q];
                float4 r;
                r.x = v.x + gate01 * fast_tanh(v.x);
                r.y = v.y + gate01 * fast_tanh(v.y);
                r.z = v.z + gate01 * fast_tanh(v.z);
                r.w = v.w + gate01 * fast_tanh(v.w);
                *(float4*)(fdst + elem) = r;
            }
        }
    }
}

__global__ __launch_bounds__(256)
void finalize_kernel(const float4* __restrict__ partials, int np,
                     float* __restrict__ out_scalars) {
    __shared__ float red[3][4];
    int tid = threadIdx.x;
    float sv = 0.f, sc = 0.f, ct = 0.f;
    for (int i = tid; i < np; i += 256) {
        float4 p = partials[i];
        sv += p.x; sc += p.y; ct += p.z;
    }
#pragma unroll
    for (int off = 32; off > 0; off >>= 1) {
        sv += __shfl_down(sv, off);
        sc += __shfl_down(sc, off);
        ct += __shfl_down(ct, off);
    }
    int lane = tid & 63, w = tid >> 6;
    if (lane == 0) { red[0][w] = sv; red[1][w] = sc; red[2][w] = ct; }
    __syncthreads();
    if (tid == 0) {
        float tv = red[0][0] + red[0][1] + red[0][2] + red[0][3];
        float tc = red[1][0] + red[1][1] + red[1][2] + red[1][3];
        float tn = red[2][0] + red[2][1] + red[2][2] + red[2][3];
        float d = tn > 1.f ? tn : 1.f;
        out_scalars[0] = tv / d;
        out_scalars[1] = tc / d;
    }
}

extern "C" void kernel_launch(void* const* d_in, const int* in_sizes, int n_in,
                              void* d_out, int out_size, void* d_ws, size_t ws_size,
                              hipStream_t stream) {
    const float* feat  = (const float*)d_in[0];
    const float* radii = (const float*)d_in[1];
    const float* w1rc  = (const float*)d_in[2];
    const float* b1rc  = (const float*)d_in[3];
    const float* w2rc  = (const float*)d_in[4];
    const float* b2rc  = (const float*)d_in[5];
    const float* w3rc  = (const float*)d_in[6];
    const float* b3rc  = (const float*)d_in[7];
    const float* w1cp  = (const float*)d_in[8];
    const float* b1cp  = (const float*)d_in[9];
    const float* w2cp  = (const float*)d_in[10];
    const float* b2cp  = (const float*)d_in[11];
    const int*   eidx  = (const int*)d_in[12];
    const int*   types = (const int*)d_in[13];

    int n = in_sizes[0] / F;          // 300000
    int m = in_sizes[12] / 2;         // 3000000

    int nblocks = (n + BLK_NODES - 1) / BLK_NODES;
    int np = nblocks * 4;
    int nbins = (n + BIN_SIZE - 1) >> BIN_SHIFT;

    // per-bin capacity: mean + 15% + 2048 slack, 256-aligned (≈30 sigma for Poisson)
    long meanb = (2L * m) / (nbins > 0 ? nbins : 1);
    int cap = (int)(((meanb * 115) / 100 + 2048 + 255) & ~255L);

    // ws layout: wt1t | wt2t | min1 | min2 | partials | counts | delta | [binned][featbf]
    char* ws = (char*)d_ws;
    short* wt1t = (short*)ws;                            ws += 128 * 192 * 2;
    short* wt2t = (short*)ws;                            ws += 48 * 128 * 2;
    int* min1 = (int*)ws;                                ws += (size_t)n * 4;
    int* min2 = (int*)ws;                                ws += (size_t)n * 4;
    float4* partials = (float4*)ws;                      ws += (size_t)np * 16;
    int* counts = (int*)ws;                              ws += NBIN_PAD * 4;
    int* delta  = (int*)ws;                              ws += NBIN_PAD * 4;

    size_t used = (size_t)(ws - (char*)d_ws);
    size_t fixed_bytes  = (size_t)nbins * cap * 4;
    size_t binned_bytes = (size_t)2 * m * 4;
    size_t featbf_bytes = (size_t)n * F * 2;

    bool okSize   = (n < (1 << 19)) && (nbins <= NBIN_PAD);
    bool useFixed = okSize && (used + fixed_bytes + featbf_bytes <= ws_size);
    bool useBinned = !useFixed && okSize && (used + binned_bytes <= ws_size);

    unsigned* binned = (unsigned*)ws;
    short* featbf;
    bool useBF, sepBuf = false;
    if (useFixed) {
        featbf = (short*)(ws + fixed_bytes);
        useBF = true;
    } else if (useBinned) {
        sepBuf = (used + binned_bytes + featbf_bytes <= ws_size);
        if (sepBuf) { featbf = (short*)(ws + binned_bytes); useBF = true; }
        else        { featbf = (short*)ws; useBF = (used + featbf_bytes) <= ws_size; }
    } else {
        featbf = (short*)ws;
        useBF = (used + featbf_bytes) <= ws_size;
    }

    float* out         = (float*)d_out;
    float* out_scalars = out + (size_t)n * F;

    int bs = 256;
    const int* e0 = eidx;
    const int* e1 = eidx + m;
    long total = (long)n * F;
    long prepthr = total / 8;
    int prepblocks = (int)((prepthr + bs - 1) / bs);

    // -------- setup (zero counts/delta + weight transposes) --------
    setup_kernel<<<121, bs, 0, stream>>>(counts, delta, w1rc, w1cp, wt1t, w2rc, w2cp, wt2t);

    // -------- edge phase --------
    if (useFixed) {
        scatter_fixed_kernel<<<768 + prepblocks, bs, 0, stream>>>(
            e0, e1, delta, binned, m, cap, 768, feat, featbf, total);
        process_fixed_kernel<<<nbins, bs, 0, stream>>>(binned, delta, min1, min2, n, cap);
    } else if (useBinned) {
        if (sepBuf && useBF) {
            count_prep_kernel<<<1024 + prepblocks, bs, 0, stream>>>(
                e0, e1, counts, m, feat, featbf, total, 1024);
        } else {
            count_prep_kernel<<<1024, bs, 0, stream>>>(
                e0, e1, counts, m, feat, featbf, 0, 1024);
        }
        scatter_kernel<<<768, bs, 0, stream>>>(e0, e1, counts, delta, binned, m);
        process_kernel<<<nbins, bs, 0, stream>>>(binned, counts, min1, min2, n);
        if (!sepBuf && useBF)
            prep_feat<<<prepblocks, bs, 0, stream>>>(feat, featbf, total);
    } else {
        int mt4 = (m + 3) / 4;
        init_min12<<<(n + bs - 1) / bs, bs, 0, stream>>>(min1, min2, n);
        edge_min1_kernel<<<(mt4 + bs - 1) / bs, bs, 0, stream>>>(e0, e1, min1, m);
        edge_min2_kernel<<<(mt4 + bs - 1) / bs, bs, 0, stream>>>(e0, e1, min1, min2, m);
        if (useBF)
            prep_feat<<<prepblocks, bs, 0, stream>>>(feat, featbf, total);
    }

    // -------- fused node + update --------
    if (useBF) {
        node_kernel<true><<<nblocks, bs, 0, stream>>>(
            feat, featbf, radii, b1rc, b2rc, w3rc, b3rc, b1cp, b2cp,
            wt1t, wt2t, types, min1, min2, out, partials, n);
    } else {
        node_kernel<false><<<nblocks, bs, 0, stream>>>(
            feat, featbf, radii, b1rc, b2rc, w3rc, b3rc, b1cp, b2cp,
            wt1t, wt2t, types, min1, min2, out, partials, n);
    }
    finalize_kernel<<<1, 256, 0, stream>>>(partials, np, out_scalars);
}

// Round 17
// 190.265 us; speedup vs baseline: 1.7543x; 1.3398x over previous
//
#include <hip/hip_runtime.h>
#include <math.h>

#define F 64
#define VIOL_THRESH 0.2f
#define BLK_NODES 128
#define H_ROWB 272   // 136 bf16 per row: 68 words ≡ 4 mod 32 banks -> 2-way (free)
#define BIN_SHIFT 11
#define BIN_SIZE 2048
#define NBIN_PAD 256
#define TILE 2048

typedef float  f32x4  __attribute__((ext_vector_type(4)));
typedef short  bf16x8 __attribute__((ext_vector_type(8)));

__device__ __forceinline__ short f2bf(float f) {
    unsigned u = __builtin_bit_cast(unsigned, f);
    unsigned r = (u + 0x7fffu + ((u >> 16) & 1u)) >> 16;
    return (short)r;
}

__device__ __forceinline__ float fexp2(float x) {
#if __has_builtin(__builtin_amdgcn_exp2f)
    return __builtin_amdgcn_exp2f(x);
#else
    return exp2f(x);
#endif
}

__device__ __forceinline__ float frcp(float x) {
#if __has_builtin(__builtin_amdgcn_rcpf)
    return __builtin_amdgcn_rcpf(x);
#else
    return 1.0f / x;
#endif
}

__device__ __forceinline__ float fast_tanh(float x) {
    float xc = fminf(fmaxf(x, -9.0f), 9.0f);
    float e = fexp2(xc * 2.885390081777927f);
    return (e - 1.0f) * frcp(e + 1.0f);
}

__device__ __forceinline__ float fast_sigmoid(float z) {
    return frcp(1.0f + fexp2(-z * 1.4426950408889634f));
}

// ---------------- fused setup: zero counts/delta + weight transposes ----------------
__global__ __launch_bounds__(256)
void setup_kernel(int* __restrict__ counts, int* __restrict__ delta,
                  const float* __restrict__ w1rc, const float* __restrict__ w1cp,
                  short* __restrict__ wt1t,
                  const float* __restrict__ w2rc, const float* __restrict__ w2cp,
                  short* __restrict__ wt2t) {
    int b = blockIdx.x, tid = threadIdx.x;
    if (b == 0) { counts[tid] = 0; delta[tid] = 0; return; }
    b -= 1;
    if (b < 24) {                      // wt2t: 48*128 = 6144 elems
        int e = b * 256 + tid;
        int o = e >> 7, k = e & 127;
        float v = 0.f;
        if (o < 32)       { if (k < 64) v = w2rc[k * 32 + o]; }
        else if (o == 32) { if (k >= 64) v = w2cp[k - 64]; }
        int kp = (k & 15) * 8 + (k >> 4);
        wt2t[o * 128 + kp] = f2bf(v);
        return;
    }
    b -= 24;
    {                                  // wt1t: 128*192 = 24576 elems
        int e = b * 256 + tid;
        int o = e / 192, k = e % 192;
        const float* src = (o < 64) ? (w1rc + o) : (w1cp + (o - 64));
        wt1t[o * 192 + k] = f2bf(src[(size_t)k * 64]);
    }
}

// ---------------- FIXED-CAPACITY scatter: 1 tile/block, int4 loads, shfl scan ----------------
__global__ __launch_bounds__(256)
void scatter_fixed_kernel(const int* __restrict__ e0, const int* __restrict__ e1,
                          int* __restrict__ delta, unsigned* __restrict__ binned,
                          int m, int cap, int sblocks,
                          const float* __restrict__ feat, short* __restrict__ featbf,
                          long total) {
    int tid = threadIdx.x;
    if ((int)blockIdx.x >= sblocks) {
        // feature bf16 prep blocks
        long t = (long)((int)blockIdx.x - sblocks) * 256 + tid;
        long base = t * 8;
        if (base >= total) return;
        float4 a = *(const float4*)(feat + base);
        float4 b = *(const float4*)(feat + base + 4);
        bf16x8 o;
        o[0] = f2bf(a.x); o[1] = f2bf(a.y); o[2] = f2bf(a.z); o[3] = f2bf(a.w);
        o[4] = f2bf(b.x); o[5] = f2bf(b.y); o[6] = f2bf(b.z); o[7] = f2bf(b.w);
        *(bf16x8*)(featbf + base) = o;
        return;
    }
    __shared__ unsigned long long buf[2 * TILE];          // 32 KB
    __shared__ int tcount[NBIN_PAD], toff[NBIN_PAD], gbase[NBIN_PAD], tcur[NBIN_PAD];
    __shared__ int wsum[4];
    __shared__ int totalsh;

    int base = (int)blockIdx.x * TILE;
    if (base >= m) return;
    int lim = min(TILE, m - base);

    // ---- load 8 edges/thread (int4 x4 when full) ----
    int ue[8], ve[8];
    int j0 = tid * 8;
    if (j0 + 8 <= lim) {
        int4 a0 = *(const int4*)(e0 + base + j0);
        int4 a1 = *(const int4*)(e0 + base + j0 + 4);
        int4 b0 = *(const int4*)(e1 + base + j0);
        int4 b1 = *(const int4*)(e1 + base + j0 + 4);
        ue[0] = a0.x; ue[1] = a0.y; ue[2] = a0.z; ue[3] = a0.w;
        ue[4] = a1.x; ue[5] = a1.y; ue[6] = a1.z; ue[7] = a1.w;
        ve[0] = b0.x; ve[1] = b0.y; ve[2] = b0.z; ve[3] = b0.w;
        ve[4] = b1.x; ve[5] = b1.y; ve[6] = b1.z; ve[7] = b1.w;
    } else {
#pragma unroll
        for (int k = 0; k < 8; k++) {
            int j = j0 + k;
            if (j < lim) { ue[k] = e0[base + j]; ve[k] = e1[base + j]; }
            else         { ue[k] = 0; ve[k] = 0; }      // u==v -> skipped
        }
    }

    tcount[tid] = 0;
    __syncthreads();
#pragma unroll
    for (int k = 0; k < 8; k++) {
        if (ue[k] != ve[k]) {
            atomicAdd(&tcount[ue[k] >> BIN_SHIFT], 1);
            atomicAdd(&tcount[ve[k] >> BIN_SHIFT], 1);
        }
    }
    __syncthreads();

    // ---- hierarchical inclusive scan (shfl within wave + 4-way combine) ----
    int c = tcount[tid];
    int v = c;
    int lane = tid & 63, w = tid >> 6;
#pragma unroll
    for (int off = 1; off < 64; off <<= 1) {
        int t = __shfl_up(v, off);
        if (lane >= off) v += t;
    }
    if (lane == 63) wsum[w] = v;
    __syncthreads();
    int pre = 0;
#pragma unroll
    for (int i = 0; i < 4; i++)
        if (i < w) pre += wsum[i];
    v += pre;
    toff[tid] = v - c;
    tcur[tid] = v - c;
    gbase[tid] = tid * cap + (c ? atomicAdd(&delta[tid], c) : 0);
    if (tid == 255) totalsh = v;
    __syncthreads();

    // ---- place into bin-sorted LDS tile ----
#pragma unroll
    for (int k = 0; k < 8; k++) {
        if (ue[k] != ve[k]) {
            int b1 = ue[k] >> BIN_SHIFT;
            int s1 = atomicAdd(&tcur[b1], 1);
            buf[s1] = ((unsigned long long)b1 << 32) |
                      (unsigned)(((ue[k] & (BIN_SIZE - 1)) << 19) | ve[k]);
            int b2 = ve[k] >> BIN_SHIFT;
            int s2 = atomicAdd(&tcur[b2], 1);
            buf[s2] = ((unsigned long long)b2 << 32) |
                      (unsigned)(((ve[k] & (BIN_SIZE - 1)) << 19) | ue[k]);
        }
    }
    __syncthreads();

    // ---- burst-drain contiguous per-bin segments ----
    int total_t = totalsh;
    for (int t = tid; t < total_t; t += 256) {
        unsigned long long e = buf[t];
        int b = (int)(e >> 32);
        binned[gbase[b] + (t - toff[b])] = (unsigned)e;
    }
}

__global__ __launch_bounds__(1024)
void process_fixed_kernel(const unsigned* __restrict__ binned, const int* __restrict__ delta,
                          int* __restrict__ min1, int* __restrict__ min2, int n, int cap) {
    __shared__ int m1s[BIN_SIZE], m2s[BIN_SIZE];   // 16 KB
    int tid = threadIdx.x, b = blockIdx.x;
    int cnt = min(delta[b], cap);
    for (int i = tid; i < BIN_SIZE; i += 1024) { m1s[i] = n; m2s[i] = n; }
    __syncthreads();
    const unsigned* bp = binned + (long)b * cap;
    int nv = cnt & ~3;
    // sweep 1: min1
    for (int j = tid * 4; j < nv; j += 4096) {
        uint4 p4 = *(const uint4*)(bp + j);
        atomicMin(&m1s[p4.x >> 19], (int)(p4.x & 0x7FFFFu));
        atomicMin(&m1s[p4.y >> 19], (int)(p4.y & 0x7FFFFu));
        atomicMin(&m1s[p4.z >> 19], (int)(p4.z & 0x7FFFFu));
        atomicMin(&m1s[p4.w >> 19], (int)(p4.w & 0x7FFFFu));
    }
    for (int j = nv + tid; j < cnt; j += 1024) {
        unsigned p = bp[j];
        atomicMin(&m1s[p >> 19], (int)(p & 0x7FFFFu));
    }
    __syncthreads();
    // sweep 2: min2 (exclude min1)
    for (int j = tid * 4; j < nv; j += 4096) {
        uint4 p4 = *(const uint4*)(bp + j);
        int lu, vv;
        lu = p4.x >> 19; vv = (int)(p4.x & 0x7FFFFu); if (vv != m1s[lu]) atomicMin(&m2s[lu], vv);
        lu = p4.y >> 19; vv = (int)(p4.y & 0x7FFFFu); if (vv != m1s[lu]) atomicMin(&m2s[lu], vv);
        lu = p4.z >> 19; vv = (int)(p4.z & 0x7FFFFu); if (vv != m1s[lu]) atomicMin(&m2s[lu], vv);
        lu = p4.w >> 19; vv = (int)(p4.w & 0x7FFFFu); if (vv != m1s[lu]) atomicMin(&m2s[lu], vv);
    }
    for (int j = nv + tid; j < cnt; j += 1024) {
        unsigned p = bp[j];
        int lu = p >> 19, vv = (int)(p & 0x7FFFFu);
        if (vv != m1s[lu]) atomicMin(&m2s[lu], vv);
    }
    __syncthreads();
    int gb = b << BIN_SHIFT;
    for (int i = tid; i < BIN_SIZE; i += 1024) {
        int g = gb + i;
        if (g < n) { min1[g] = m1s[i]; min2[g] = m2s[i]; }
    }
}

// ---------------- compact-binned fallback (count + scan) ----------------
__global__ __launch_bounds__(256)
void count_prep_kernel(const int* __restrict__ e0, const int* __restrict__ e1,
                       int* __restrict__ counts, int m,
                       const float* __restrict__ feat, short* __restrict__ featbf,
                       long total, int cblocks) {
    int tid = threadIdx.x;
    if ((int)blockIdx.x < cblocks) {
        __shared__ int c[NBIN_PAD];
        c[tid] = 0;
        __syncthreads();
        for (long j = (long)blockIdx.x * 256 + tid; j < m; j += (long)cblocks * 256) {
            int u = e0[j], v = e1[j];
            if (u != v) {
                atomicAdd(&c[u >> BIN_SHIFT], 1);
                atomicAdd(&c[v >> BIN_SHIFT], 1);
            }
        }
        __syncthreads();
        if (c[tid]) atomicAdd(&counts[tid], c[tid]);
    } else {
        long t = (long)((int)blockIdx.x - cblocks) * 256 + tid;
        long base = t * 8;
        if (base >= total) return;
        float4 a = *(const float4*)(feat + base);
        float4 b = *(const float4*)(feat + base + 4);
        bf16x8 o;
        o[0] = f2bf(a.x); o[1] = f2bf(a.y); o[2] = f2bf(a.z); o[3] = f2bf(a.w);
        o[4] = f2bf(b.x); o[5] = f2bf(b.y); o[6] = f2bf(b.z); o[7] = f2bf(b.w);
        *(bf16x8*)(featbf + base) = o;
    }
}

__global__ __launch_bounds__(256)
void scatter_kernel(const int* __restrict__ e0, const int* __restrict__ e1,
                    const int* __restrict__ counts, int* __restrict__ delta,
                    unsigned* __restrict__ binned, int m) {
    __shared__ unsigned long long buf[2 * TILE];
    __shared__ int goff[NBIN_PAD];
    __shared__ int tcount[NBIN_PAD], toff[NBIN_PAD], tmp[NBIN_PAD];
    __shared__ int gbase[NBIN_PAD], tcur[NBIN_PAD];
    __shared__ int totalsh;
    int tid = threadIdx.x;

    int c = counts[tid];
    tmp[tid] = c;
    __syncthreads();
    for (int off = 1; off < NBIN_PAD; off <<= 1) {
        int v = (tid >= off) ? tmp[tid - off] : 0;
        __syncthreads();
        tmp[tid] += v;
        __syncthreads();
    }
    goff[tid] = tmp[tid] - c;
    __syncthreads();

    int ntile = (m + TILE - 1) / TILE;
    for (int tile = blockIdx.x; tile < ntile; tile += gridDim.x) {
        int base = tile * TILE;
        int lim = min(TILE, m - base);
        tcount[tid] = 0;
        __syncthreads();
        for (int j = tid; j < lim; j += 256) {
            int u = e0[base + j], v = e1[base + j];
            if (u != v) {
                atomicAdd(&tcount[u >> BIN_SHIFT], 1);
                atomicAdd(&tcount[v >> BIN_SHIFT], 1);
            }
        }
        __syncthreads();
        tmp[tid] = tcount[tid];
        __syncthreads();
        for (int off = 1; off < NBIN_PAD; off <<= 1) {
            int vv = (tid >= off) ? tmp[tid - off] : 0;
            __syncthreads();
            tmp[tid] += vv;
            __syncthreads();
        }
        toff[tid] = tmp[tid] - tcount[tid];
        if (tid == NBIN_PAD - 1) totalsh = tmp[NBIN_PAD - 1];
        {
            int cct = tcount[tid];
            gbase[tid] = goff[tid] + (cct ? atomicAdd(&delta[tid], cct) : 0);
            tcur[tid] = tmp[tid] - cct;
        }
        __syncthreads();
        for (int j = tid; j < lim; j += 256) {
            int u = e0[base + j], v = e1[base + j];
            if (u != v) {
                int b1 = u >> BIN_SHIFT;
                int s1 = atomicAdd(&tcur[b1], 1);
                buf[s1] = ((unsigned long long)b1 << 32) |
                          (unsigned)(((u & (BIN_SIZE - 1)) << 19) | v);
                int b2 = v >> BIN_SHIFT;
                int s2 = atomicAdd(&tcur[b2], 1);
                buf[s2] = ((unsigned long long)b2 << 32) |
                          (unsigned)(((v & (BIN_SIZE - 1)) << 19) | u);
            }
        }
        __syncthreads();
        int total = totalsh;
        for (int t = tid; t < total; t += 256) {
            unsigned long long e = buf[t];
            int b = (int)(e >> 32);
            binned[gbase[b] + (t - toff[b])] = (unsigned)e;
        }
        __syncthreads();
    }
}

__global__ __launch_bounds__(256)
void process_kernel(const unsigned* __restrict__ binned, const int* __restrict__ counts,
                    int* __restrict__ min1, int* __restrict__ min2, int n) {
    __shared__ int m1s[BIN_SIZE], m2s[BIN_SIZE];
    __shared__ int tmp[NBIN_PAD];
    __shared__ int s_sh, e_sh;
    int tid = threadIdx.x, b = blockIdx.x;
    int c = counts[tid];
    tmp[tid] = c;
    __syncthreads();
    for (int off = 1; off < NBIN_PAD; off <<= 1) {
        int v = (tid >= off) ? tmp[tid - off] : 0;
        __syncthreads();
        tmp[tid] += v;
        __syncthreads();
    }
    if (tid == b) { e_sh = tmp[tid]; s_sh = tmp[tid] - c; }
    for (int i = tid; i < BIN_SIZE; i += 256) { m1s[i] = n; m2s[i] = n; }
    __syncthreads();
    int s = s_sh, e = e_sh;
    for (int j = s + tid; j < e; j += 256) {
        unsigned p = binned[j];
        atomicMin(&m1s[p >> 19], (int)(p & 0x7FFFFu));
    }
    __syncthreads();
    for (int j = s + tid; j < e; j += 256) {
        unsigned p = binned[j];
        int lu = p >> 19, v = (int)(p & 0x7FFFFu);
        if (v != m1s[lu]) atomicMin(&m2s[lu], v);
    }
    __syncthreads();
    int gb = b << BIN_SHIFT;
    for (int i = tid; i < BIN_SIZE; i += 256) {
        int g = gb + i;
        if (g < n) { min1[g] = m1s[i]; min2[g] = m2s[i]; }
    }
}

// ---------------- device-scope fallback ----------------
__global__ void init_min12(int* __restrict__ min1, int* __restrict__ min2, int n) {
    int i = blockIdx.x * blockDim.x + threadIdx.x;
    if (i < n) { min1[i] = n; min2[i] = n; }
}

__device__ __forceinline__ void upd_min1(int u, int v, int* __restrict__ min1) {
    if (u != v) {
        if (v < min1[u]) atomicMin(&min1[u], v);
        if (u < min1[v]) atomicMin(&min1[v], u);
    }
}

__global__ void edge_min1_kernel(const int* __restrict__ e0, const int* __restrict__ e1,
                                 int* __restrict__ min1, int m) {
    int t = blockIdx.x * blockDim.x + threadIdx.x;
    int base = t * 4;
    if (base >= m) return;
    if (base + 4 <= m) {
        int4 u4 = *(const int4*)(e0 + base);
        int4 v4 = *(const int4*)(e1 + base);
        upd_min1(u4.x, v4.x, min1);
        upd_min1(u4.y, v4.y, min1);
        upd_min1(u4.z, v4.z, min1);
        upd_min1(u4.w, v4.w, min1);
    } else {
        for (int j = base; j < m; j++) upd_min1(e0[j], e1[j], min1);
    }
}

__device__ __forceinline__ void upd_min2(int u, int v, const int* __restrict__ min1,
                                         int* __restrict__ min2) {
    if (u != v) {
        if (v != min1[u] && v < min2[u]) atomicMin(&min2[u], v);
        if (u != min1[v] && u < min2[v]) atomicMin(&min2[v], u);
    }
}

__global__ void edge_min2_kernel(const int* __restrict__ e0, const int* __restrict__ e1,
                                 const int* __restrict__ min1, int* __restrict__ min2, int m) {
    int t = blockIdx.x * blockDim.x + threadIdx.x;
    int base = t * 4;
    if (base >= m) return;
    if (base + 4 <= m) {
        int4 u4 = *(const int4*)(e0 + base);
        int4 v4 = *(const int4*)(e1 + base);
        upd_min2(u4.x, v4.x, min1, min2);
        upd_min2(u4.y, v4.y, min1, min2);
        upd_min2(u4.z, v4.z, min1, min2);
        upd_min2(u4.w, v4.w, min1, min2);
    } else {
        for (int j = base; j < m; j++) upd_min2(e0[j], e1[j], min1, min2);
    }
}

// ---------------- standalone feature bf16 prep ----------------
__global__ void prep_feat(const float* __restrict__ f, short* __restrict__ fb, long total) {
    long t = (long)blockIdx.x * blockDim.x + threadIdx.x;
    long base = t * 8;
    if (base >= total) return;
    float4 a = *(const float4*)(f + base);
    float4 b = *(const float4*)(f + base + 4);
    bf16x8 o;
    o[0] = f2bf(a.x); o[1] = f2bf(a.y); o[2] = f2bf(a.z); o[3] = f2bf(a.w);
    o[4] = f2bf(b.x); o[5] = f2bf(b.y); o[6] = f2bf(b.z); o[7] = f2bf(b.w);
    *(bf16x8*)(fb + base) = o;
}

// ---------------- fused node + feature-update kernel (2 m-tiles/wave, early update loads) ----------------
template<bool BF>
__global__ __launch_bounds__(256)
void node_kernel(const float* __restrict__ feat, const short* __restrict__ featbf,
                 const float* __restrict__ radii,
                 const float* __restrict__ b1rc, const float* __restrict__ b2rc,
                 const float* __restrict__ w3rc, const float* __restrict__ b3rc,
                 const float* __restrict__ b1cp, const float* __restrict__ b2cp,
                 const short* __restrict__ wt1t, const short* __restrict__ wt2t,
                 const int* __restrict__ types,
                 const int* __restrict__ min1, const int* __restrict__ min2,
                 float* __restrict__ out, float4* __restrict__ partials,
                 int n) {
    __shared__ __align__(16) char Hbuf[BLK_NODES * H_ROWB];
    __shared__ float corrArr[BLK_NODES];
    __shared__ float zArr[BLK_NODES];
    __shared__ float gateArr[BLK_NODES];

    int tid = threadIdx.x;
    int blk = blockIdx.x;
    int lane = tid & 63;
    int w = tid >> 6;
    int lm = lane & 15;
    int lg = lane >> 4;
    int wnb = w * 32;

    int nid[2][3];
#pragma unroll
    for (int mt = 0; mt < 2; mt++) {
        int g = blk * BLK_NODES + wnb + mt * 16 + lm;
        int ii = (g < n) ? g : (n - 1);
        int m1 = min1[ii];
        int m2 = min2[ii];
        nid[mt][0] = ii;
        nid[mt][1] = (m1 < n) ? m1 : (n - 1);
        nid[mt][2] = (m2 < n) ? m2 : (n - 1);
    }

    // ---- EARLY update-stream loads ----
    size_t wbase = (size_t)(blk * BLK_NODES + wnb) * F;
    const float* fsrc = feat + wbase;
    float4 updv[8];
#pragma unroll
    for (int q = 0; q < 8; q++) {
        int elem = q * 256 + lane * 4;
        int g = blk * BLK_NODES + wnb + (elem >> 6);
        updv[q] = (g < n) ? *(const float4*)(fsrc + elem)
                          : (float4){0.f, 0.f, 0.f, 0.f};
    }

    // ---- early epilogue prefetch ----
    int el = lane & 31;
    int eg = blk * BLK_NODES + wnb + el;
    bool elive = eg < n;
    int eii = elive ? eg : (n - 1);
    int em1 = min1[eii];
    int em2 = min2[eii];
    float er0 = radii[eii];
    int ety = types[eii];
    int ec1 = (em1 < n) ? em1 : (n - 1);
    int ec2 = (em2 < n) ? em2 : (n - 1);
    float er1 = radii[ec1];
    float er2 = radii[ec2];

    bf16x8 af[2][3][2];
    if constexpr (BF) {
#pragma unroll
        for (int mt = 0; mt < 2; mt++)
#pragma unroll
            for (int part = 0; part < 3; part++)
#pragma unroll
                for (int h = 0; h < 2; h++)
                    af[mt][part][h] = *(const bf16x8*)(featbf + (size_t)nid[mt][part] * F + h * 32 + lg * 8);
    }

    f32x4 zero4 = {0.f, 0.f, 0.f, 0.f};
    f32x4 acc[2][8];
#pragma unroll
    for (int mt = 0; mt < 2; mt++)
#pragma unroll
        for (int nt = 0; nt < 8; nt++) acc[mt][nt] = zero4;

#pragma unroll
    for (int s = 0; s < 6; s++) {
        int part = s >> 1;
        int h = s & 1;
        bf16x8 a0, a1;
        if constexpr (BF) {
            a0 = af[0][part][h];
            a1 = af[1][part][h];
        } else {
#pragma unroll
            for (int mt = 0; mt < 2; mt++) {
                const float* rp = feat + (size_t)nid[mt][part] * F + h * 32 + lg * 8;
                float4 f0 = *(const float4*)rp;
                float4 f1 = *(const float4*)(rp + 4);
                bf16x8 a;
                a[0] = f2bf(f0.x); a[1] = f2bf(f0.y); a[2] = f2bf(f0.z); a[3] = f2bf(f0.w);
                a[4] = f2bf(f1.x); a[5] = f2bf(f1.y); a[6] = f2bf(f1.z); a[7] = f2bf(f1.w);
                if (mt == 0) a0 = a; else a1 = a;
            }
        }
#pragma unroll
        for (int nt = 0; nt < 8; nt++) {
            bf16x8 b = *(const bf16x8*)(wt1t + (lm + 16 * nt) * 192 + s * 32 + lg * 8);
            acc[0][nt] = __builtin_amdgcn_mfma_f32_16x16x32_bf16(a0, b, acc[0][nt], 0, 0, 0);
            acc[1][nt] = __builtin_amdgcn_mfma_f32_16x16x32_bf16(a1, b, acc[1][nt], 0, 0, 0);
        }
    }

    float b1v[8];
#pragma unroll
    for (int nt = 0; nt < 8; nt++)
        b1v[nt] = (nt < 4) ? b1rc[lm + 16 * nt] : b1cp[lm + 16 * nt - 64];

#pragma unroll
    for (int mt = 0; mt < 2; mt++) {
#pragma unroll
        for (int r = 0; r < 4; r++) {
            int node = wnb + mt * 16 + lg * 4 + r;
            bf16x8 hv;
#pragma unroll
            for (int nt = 0; nt < 8; nt++)
                hv[nt] = f2bf(fmaxf(acc[mt][nt][r] + b1v[nt], 0.f));
            *(bf16x8*)(Hbuf + node * H_ROWB + lm * 16) = hv;
        }
    }

    f32x4 acc2[2][3];
#pragma unroll
    for (int mt = 0; mt < 2; mt++)
#pragma unroll
        for (int nt = 0; nt < 3; nt++) acc2[mt][nt] = zero4;

#pragma unroll
    for (int s = 0; s < 4; s++) {
        bf16x8 af2[2];
#pragma unroll
        for (int mt = 0; mt < 2; mt++)
            af2[mt] = *(const bf16x8*)(Hbuf + (wnb + mt * 16 + lm) * H_ROWB + s * 64 + lg * 16);
#pragma unroll
        for (int nt = 0; nt < 3; nt++) {
            bf16x8 b = *(const bf16x8*)(wt2t + (lm + 16 * nt) * 128 + s * 32 + lg * 8);
            acc2[0][nt] = __builtin_amdgcn_mfma_f32_16x16x32_bf16(af2[0], b, acc2[0][nt], 0, 0, 0);
            acc2[1][nt] = __builtin_amdgcn_mfma_f32_16x16x32_bf16(af2[1], b, acc2[1][nt], 0, 0, 0);
        }
    }

#pragma unroll
    for (int mt = 0; mt < 2; mt++) {
#pragma unroll
        for (int r = 0; r < 4; r++) {
            float t = 0.f;
#pragma unroll
            for (int nt = 0; nt < 2; nt++) {
                int o = lm + 16 * nt;
                float s2v = fmaxf(acc2[mt][nt][r] + b2rc[o], 0.f);
                t = fmaf(s2v, w3rc[o], t);
            }
            float zz = acc2[mt][2][r];
#pragma unroll
            for (int msk = 1; msk < 16; msk <<= 1) {
                t  += __shfl_xor(t, msk);
                zz += __shfl_xor(zz, msk);
            }
            if (lm == 0) {
                int node = wnb + mt * 16 + lg * 4 + r;
                corrArr[node] = t + b3rc[0];
                zArr[node]    = zz + b2cp[0];
            }
        }
    }

    // ---------- per-wave epilogue ----------
    float sv = 0.f, sc = 0.f, ct = 0.f;
    if (lane < 32) {
        bool valid = em2 < n;
        float pr3 = er0 * er0 * er0;
        float viol = fabsf(er1 * er1 * er1 + er2 * er2 * er2 - pr3) / pr3;
        bool active = elive && valid && (ety == 1);
        bool upd = active && (viol > VIOL_THRESH);
        float gate = upd ? corrArr[wnb + el] : 0.f;
        gateArr[wnb + el] = 0.1f * gate;
        if (active) {
            sv = viol;
            sc = fast_sigmoid(zArr[wnb + el]);
            ct = 1.f;
        }
    }
#pragma unroll
    for (int off = 32; off > 0; off >>= 1) {
        sv += __shfl_down(sv, off);
        sc += __shfl_down(sc, off);
        ct += __shfl_down(ct, off);
    }
    if (lane == 0) {
        float4 p; p.x = sv; p.y = sc; p.z = ct; p.w = 0.f;
        partials[blk * 4 + w] = p;
    }

    // ---------- feature update (data in registers) ----------
    {
        float* fdst = out + wbase;
#pragma unroll
        for (int q = 0; q < 8; q++) {
            int elem = q * 256 + lane * 4;
            int nloc = wnb + (elem >> 6);
            int g = blk * BLK_NODES + nloc;
            if (g < n) {
                float gate01 = gateArr[nloc];
                float4 v = updv[q];
                float4 r;
                r.x = v.x + gate01 * fast_tanh(v.x);
                r.y = v.y + gate01 * fast_tanh(v.y);
                r.z = v.z + gate01 * fast_tanh(v.z);
                r.w = v.w + gate01 * fast_tanh(v.w);
                *(float4*)(fdst + elem) = r;
            }
        }
    }
}

__global__ __launch_bounds__(256)
void finalize_kernel(const float4* __restrict__ partials, int np,
                     float* __restrict__ out_scalars) {
    __shared__ float red[3][4];
    int tid = threadIdx.x;
    float sv = 0.f, sc = 0.f, ct = 0.f;
    for (int i = tid; i < np; i += 256) {
        float4 p = partials[i];
        sv += p.x; sc += p.y; ct += p.z;
    }
#pragma unroll
    for (int off = 32; off > 0; off >>= 1) {
        sv += __shfl_down(sv, off);
        sc += __shfl_down(sc, off);
        ct += __shfl_down(ct, off);
    }
    int lane = tid & 63, w = tid >> 6;
    if (lane == 0) { red[0][w] = sv; red[1][w] = sc; red[2][w] = ct; }
    __syncthreads();
    if (tid == 0) {
        float tv = red[0][0] + red[0][1] + red[0][2] + red[0][3];
        float tc = red[1][0] + red[1][1] + red[1][2] + red[1][3];
        float tn = red[2][0] + red[2][1] + red[2][2] + red[2][3];
        float d = tn > 1.f ? tn : 1.f;
        out_scalars[0] = tv / d;
        out_scalars[1] = tc / d;
    }
}

extern "C" void kernel_launch(void* const* d_in, const int* in_sizes, int n_in,
                              void* d_out, int out_size, void* d_ws, size_t ws_size,
                              hipStream_t stream) {
    const float* feat  = (const float*)d_in[0];
    const float* radii = (const float*)d_in[1];
    const float* w1rc  = (const float*)d_in[2];
    const float* b1rc  = (const float*)d_in[3];
    const float* w2rc  = (const float*)d_in[4];
    const float* b2rc  = (const float*)d_in[5];
    const float* w3rc  = (const float*)d_in[6];
    const float* b3rc  = (const float*)d_in[7];
    const float* w1cp  = (const float*)d_in[8];
    const float* b1cp  = (const float*)d_in[9];
    const float* w2cp  = (const float*)d_in[10];
    const float* b2cp  = (const float*)d_in[11];
    const int*   eidx  = (const int*)d_in[12];
    const int*   types = (const int*)d_in[13];

    int n = in_sizes[0] / F;          // 300000
    int m = in_sizes[12] / 2;         // 3000000

    int nblocks = (n + BLK_NODES - 1) / BLK_NODES;
    int np = nblocks * 4;
    int nbins = (n + BIN_SIZE - 1) >> BIN_SHIFT;

    // per-bin capacity: mean + 15% + 2048 slack, 256-aligned (≈30 sigma for Poisson)
    long meanb = (2L * m) / (nbins > 0 ? nbins : 1);
    int cap = (int)(((meanb * 115) / 100 + 2048 + 255) & ~255L);

    // ws layout: wt1t | wt2t | min1 | min2 | partials | counts | delta | [binned][featbf]
    char* ws = (char*)d_ws;
    short* wt1t = (short*)ws;                            ws += 128 * 192 * 2;
    short* wt2t = (short*)ws;                            ws += 48 * 128 * 2;
    int* min1 = (int*)ws;                                ws += (size_t)n * 4;
    int* min2 = (int*)ws;                                ws += (size_t)n * 4;
    float4* partials = (float4*)ws;                      ws += (size_t)np * 16;
    int* counts = (int*)ws;                              ws += NBIN_PAD * 4;
    int* delta  = (int*)ws;                              ws += NBIN_PAD * 4;

    size_t used = (size_t)(ws - (char*)d_ws);
    size_t fixed_bytes  = (size_t)nbins * cap * 4;
    size_t binned_bytes = (size_t)2 * m * 4;
    size_t featbf_bytes = (size_t)n * F * 2;

    bool okSize   = (n < (1 << 19)) && (nbins <= NBIN_PAD);
    bool useFixed = okSize && (used + fixed_bytes + featbf_bytes <= ws_size);
    bool useBinned = !useFixed && okSize && (used + binned_bytes <= ws_size);

    unsigned* binned = (unsigned*)ws;
    short* featbf;
    bool useBF, sepBuf = false;
    if (useFixed) {
        featbf = (short*)(ws + fixed_bytes);
        useBF = true;
    } else if (useBinned) {
        sepBuf = (used + binned_bytes + featbf_bytes <= ws_size);
        if (sepBuf) { featbf = (short*)(ws + binned_bytes); useBF = true; }
        else        { featbf = (short*)ws; useBF = (used + featbf_bytes) <= ws_size; }
    } else {
        featbf = (short*)ws;
        useBF = (used + featbf_bytes) <= ws_size;
    }

    float* out         = (float*)d_out;
    float* out_scalars = out + (size_t)n * F;

    int bs = 256;
    const int* e0 = eidx;
    const int* e1 = eidx + m;
    long total = (long)n * F;
    long prepthr = total / 8;
    int prepblocks = (int)((prepthr + bs - 1) / bs);

    // -------- setup (zero counts/delta + weight transposes) --------
    setup_kernel<<<121, bs, 0, stream>>>(counts, delta, w1rc, w1cp, wt1t, w2rc, w2cp, wt2t);

    // -------- edge phase --------
    if (useFixed) {
        int ntile = (m + TILE - 1) / TILE;
        scatter_fixed_kernel<<<ntile + prepblocks, bs, 0, stream>>>(
            e0, e1, delta, binned, m, cap, ntile, feat, featbf, total);
        process_fixed_kernel<<<nbins, 1024, 0, stream>>>(binned, delta, min1, min2, n, cap);
    } else if (useBinned) {
        if (sepBuf && useBF) {
            count_prep_kernel<<<1024 + prepblocks, bs, 0, stream>>>(
                e0, e1, counts, m, feat, featbf, total, 1024);
        } else {
            count_prep_kernel<<<1024, bs, 0, stream>>>(
                e0, e1, counts, m, feat, featbf, 0, 1024);
        }
        scatter_kernel<<<768, bs, 0, stream>>>(e0, e1, counts, delta, binned, m);
        process_kernel<<<nbins, bs, 0, stream>>>(binned, counts, min1, min2, n);
        if (!sepBuf && useBF)
            prep_feat<<<prepblocks, bs, 0, stream>>>(feat, featbf, total);
    } else {
        int mt4 = (m + 3) / 4;
        init_min12<<<(n + bs - 1) / bs, bs, 0, stream>>>(min1, min2, n);
        edge_min1_kernel<<<(mt4 + bs - 1) / bs, bs, 0, stream>>>(e0, e1, min1, m);
        edge_min2_kernel<<<(mt4 + bs - 1) / bs, bs, 0, stream>>>(e0, e1, min1, min2, m);
        if (useBF)
            prep_feat<<<prepblocks, bs, 0, stream>>>(feat, featbf, total);
    }

    // -------- fused node + update --------
    if (useBF) {
        node_kernel<true><<<nblocks, bs, 0, stream>>>(
            feat, featbf, radii, b1rc, b2rc, w3rc, b3rc, b1cp, b2cp,
            wt1t, wt2t, types, min1, min2, out, partials, n);
    } else {
        node_kernel<false><<<nblocks, bs, 0, stream>>>(
            feat, featbf, radii, b1rc, b2rc, w3rc, b3rc, b1cp, b2cp,
            wt1t, wt2t, types, min1, min2, out, partials, n);
    }
    finalize_kernel<<<1, 256, 0, stream>>>(partials, np, out_scalars);
}